// Round 3
// baseline (1253.795 us; speedup 1.0000x reference)
//
#include <hip/hip_runtime.h>

#define N_NODES  50000
#define N_EDGES  500000
#define N_GRAPHS 2000
#define HID      145
#define HID2     72
#define N_LAYERS 4
#define EPS      1e-5f
#define HWS_LD   160   // padded row stride for gather target: 640B = 5 aligned 128B lines
#define BR       32    // rows per GEMM block
#define TLD      148   // LDS tile stride (floats): 16B-aligned rows, 37 odd -> bank-free
#define NC       19    // cols per thread chunk (8 chunks of 18 + 1 overlap cover 145)
#define NSTAT    256   // bnstat partial blocks

// ---------------- CSR build ----------------

__global__ void k_hist(const int* __restrict__ col, int* __restrict__ hist) {
    int i = blockIdx.x * 256 + threadIdx.x;
    if (i < N_EDGES) atomicAdd(&hist[col[i]], 1);
}

__global__ void k_scan1(const int* __restrict__ cnt, int* __restrict__ incl,
                        int* __restrict__ part) {
    __shared__ int s[1024];
    int i = blockIdx.x * 1024 + threadIdx.x;
    int v = (i < N_NODES) ? cnt[i] : 0;
    s[threadIdx.x] = v;
    __syncthreads();
    for (int d = 1; d < 1024; d <<= 1) {
        int t = (threadIdx.x >= d) ? s[threadIdx.x - d] : 0;
        __syncthreads();
        s[threadIdx.x] += t;
        __syncthreads();
    }
    if (i < N_NODES) incl[i] = s[threadIdx.x];
    if (threadIdx.x == 1023) part[blockIdx.x] = s[1023];
}

__global__ void k_scan2(int* part, int nb) {
    if (threadIdx.x == 0 && blockIdx.x == 0) {
        int acc = 0;
        for (int b = 0; b < nb; b++) { int t = part[b]; part[b] = acc; acc += t; }
    }
}

__global__ void k_scan3(const int* __restrict__ incl, const int* __restrict__ cnt,
                        const int* __restrict__ part, int* __restrict__ starts,
                        int* __restrict__ cursor, float* __restrict__ dis) {
    int i = blockIdx.x * 1024 + threadIdx.x;
    if (i < N_NODES) {
        int st = incl[i] - cnt[i] + part[blockIdx.x];
        starts[i] = st;
        cursor[i] = st;
        dis[i] = rsqrtf((float)(cnt[i] + 1));  // +1 self loop
    }
    if (i == 0) starts[N_NODES] = N_EDGES;
}

__global__ void k_fill(const int* __restrict__ rowv, const int* __restrict__ colv,
                       int* __restrict__ cursor, int* __restrict__ csr) {
    int e = blockIdx.x * 256 + threadIdx.x;
    if (e < N_EDGES) {
        int c = colv[e];
        int p = atomicAdd(&cursor[c], 1);
        csr[p] = rowv[e];
    }
}

// ---------------- fused (BN-apply | embed) + GEMM ----------------
// Phase 1: h_new = relu(A*agg+B) + h_old (in place, MODE 1) or emb[x] (MODE 0),
//          written to global h and LDS tile (stride TLD).
// Phase 2: 32 rows x 8 col-chunks of 19 (chunks overlap 1 col; duplicate writes
//          are bit-identical). Epilogue scales by dis -> hws.

template <int MODE>
__global__ __launch_bounds__(256, 6) void k_gemm_fused(
    const float* __restrict__ Wl, const float* __restrict__ dis,
    const int* __restrict__ x, const float* __restrict__ emb,
    const float* __restrict__ agg, const float* __restrict__ AB,
    float* __restrict__ h, float* __restrict__ hws) {
    __shared__ float tile[BR * TLD];
    __shared__ float sA[HID], sB[HID];
    int t = threadIdx.x;
    int rbase = blockIdx.x * BR;
    if (MODE == 1 && t < HID) { sA[t] = AB[t]; sB[t] = AB[HID + t]; }
    __syncthreads();
    for (int e = t; e < BR * HID; e += 256) {
        int r = e / HID;
        int f = e - r * HID;
        int gr = rbase + r;
        float v = 0.f;
        if (gr < N_NODES) {
            size_t idx = (size_t)gr * HID + f;
            if (MODE == 0) {
                v = emb[x[gr] * HID + f];
            } else {
                v = fmaf(sA[f], agg[idx], sB[f]);
                v = fmaxf(v, 0.f) + h[idx];
            }
            h[idx] = v;
        }
        tile[r * TLD + f] = v;
    }
    __syncthreads();
    int row = t & (BR - 1);
    int cidx = t >> 5;           // 0..7
    int c0 = cidx * 18;          // chunk covers [c0, c0+19)
    int gr = rbase + row;
    float acc[NC];
#pragma unroll
    for (int c = 0; c < NC; c++) acc[c] = 0.f;
    const float* tr = tile + row * TLD;
    const float* wp = Wl + c0;
    for (int k = 0; k < HID; k++) {
        float a = tr[k];
        const float* wr = wp + k * HID;
#pragma unroll
        for (int c = 0; c < NC; c++) acc[c] = fmaf(a, wr[c], acc[c]);
    }
    if (gr < N_NODES) {
        float d = dis[gr];
        float* o = hws + (size_t)gr * HWS_LD + c0;
#pragma unroll
        for (int c = 0; c < NC; c++) o[c] = acc[c] * d;
    }
}

// ---------------- aggregate: agg[i] = dis[i] * (sum_{src in N(i)} hws[src] + hws[i])
// one wave per node; fully-predicated 4-wide edge loop (12 row-loads in flight).

__global__ __launch_bounds__(256) void k_agg(const float* __restrict__ hws,
                                             const int* __restrict__ starts,
                                             const int* __restrict__ csr,
                                             const float* __restrict__ dis,
                                             float* __restrict__ agg) {
    int wave = threadIdx.x >> 6;
    int lane = threadIdx.x & 63;
    int i = blockIdx.x * 4 + wave;
    if (i >= N_NODES) return;
    int s = starts[i], e = starts[i + 1];
    int f0 = lane, f1 = lane + 64, f2 = lane + 128;
    bool p2 = f2 < HID;
    const float* self = hws + (size_t)i * HWS_LD;
    float a0 = self[f0];
    float a1 = self[f1];
    float a2 = p2 ? self[f2] : 0.f;
    int last = e - 1;
    for (int j = s; j < e; j += 4) {
        int j1 = j + 1 < e ? j + 1 : last;
        int j2 = j + 2 < e ? j + 2 : last;
        int j3 = j + 3 < e ? j + 3 : last;
        int s0 = csr[j], s1 = csr[j1], s2 = csr[j2], s3 = csr[j3];
        const float* q0 = hws + (size_t)s0 * HWS_LD;
        const float* q1 = hws + (size_t)s1 * HWS_LD;
        const float* q2 = hws + (size_t)s2 * HWS_LD;
        const float* q3 = hws + (size_t)s3 * HWS_LD;
        float m1 = (j + 1 < e) ? 1.f : 0.f;
        float m2 = (j + 2 < e) ? 1.f : 0.f;
        float m3 = (j + 3 < e) ? 1.f : 0.f;
        a0 += q0[f0] + m1 * q1[f0] + m2 * q2[f0] + m3 * q3[f0];
        a1 += q0[f1] + m1 * q1[f1] + m2 * q2[f1] + m3 * q3[f1];
        if (p2) a2 += q0[f2] + m1 * q1[f2] + m2 * q2[f2] + m3 * q3[f2];
    }
    float di = dis[i];
    float* o = agg + (size_t)i * HID;
    o[f0] = a0 * di;
    o[f1] = a1 * di;
    if (p2) o[f2] = a2 * di;
}

// ---------------- BatchNorm stats ----------------

__global__ __launch_bounds__(192) void k_bnstat(const float* __restrict__ agg,
                                                float* __restrict__ partial) {
    int t = threadIdx.x;
    if (t >= HID) return;
    float s = 0.f, q = 0.f;
    for (int r = blockIdx.x; r < N_NODES; r += NSTAT) {
        float v = agg[(size_t)r * HID + t];
        s += v;
        q = fmaf(v, v, q);
    }
    partial[blockIdx.x * (2 * HID) + t] = s;
    partial[blockIdx.x * (2 * HID) + HID + t] = q;
}

__global__ __launch_bounds__(192) void k_bncoef(const float* __restrict__ partial,
                                                const float* __restrict__ gamma,
                                                const float* __restrict__ beta,
                                                float* __restrict__ AB) {
    int f = threadIdx.x;
    if (f >= HID) return;
    float s = 0.f, q = 0.f;
    for (int b = 0; b < NSTAT; b++) {
        s += partial[b * (2 * HID) + f];
        q += partial[b * (2 * HID) + HID + f];
    }
    const float inv = 1.f / (float)N_NODES;
    float mu = s * inv;
    float var = q * inv - mu * mu;
    float a = gamma[f] * rsqrtf(var + EPS);
    AB[f] = a;
    AB[HID + f] = beta[f] - mu * a;
}

// ---------------- pool (fused with layer-3 BN apply) + MLP ----------------

__global__ __launch_bounds__(192) void k_pool(const float* __restrict__ agg,
                                              const float* __restrict__ h,
                                              const float* __restrict__ AB,
                                              const int* __restrict__ batch,
                                              float* __restrict__ hg) {
    int g = blockIdx.x;
    int lo = 0, hi = N_NODES;
    while (lo < hi) { int m = (lo + hi) >> 1; if (batch[m] < g) lo = m + 1; else hi = m; }
    int s = lo;
    hi = N_NODES;
    while (lo < hi) { int m = (lo + hi) >> 1; if (batch[m] < g + 1) lo = m + 1; else hi = m; }
    int e = lo;
    int f = threadIdx.x;
    if (f >= HID) return;
    float A = AB[f], B = AB[HID + f];
    float acc = 0.f;
    for (int n = s; n < e; n++) {
        size_t idx = (size_t)n * HID + f;
        float v = fmaf(A, agg[idx], B);
        acc += fmaxf(v, 0.f) + h[idx];
    }
    hg[g * HID + f] = acc / fmaxf((float)(e - s), 1.f);
}

__global__ __launch_bounds__(128) void k_mlp(const float* __restrict__ hg,
                                             const float* __restrict__ W1,
                                             const float* __restrict__ b1,
                                             const float* __restrict__ W2,
                                             const float* __restrict__ b2,
                                             float* __restrict__ out) {
    int g = blockIdx.x;
    int t = threadIdx.x;
    float v = 0.f;
    if (t < HID2) {
        float s = b1[t];
        const float* hgr = hg + g * HID;
        for (int k = 0; k < HID; k++) s = fmaf(hgr[k], W1[k * HID2 + t], s);
        v = fmaxf(s, 0.f) * W2[t];
    }
    __shared__ float red[128];
    red[t] = v;
    __syncthreads();
    for (int d = 64; d > 0; d >>= 1) {
        if (t < d) red[t] += red[t + d];
        __syncthreads();
    }
    if (t == 0) out[g] = red[0] + b2[0];
}

// ---------------- host launch ----------------

extern "C" void kernel_launch(void* const* d_in, const int* in_sizes, int n_in,
                              void* d_out, int out_size, void* d_ws, size_t ws_size,
                              hipStream_t stream) {
    const int*   x     = (const int*)d_in[0];
    const int*   erow  = (const int*)d_in[1];
    const int*   ecol  = erow + N_EDGES;
    const int*   batch = (const int*)d_in[2];
    const float* emb   = (const float*)d_in[3];
    const float* Wc    = (const float*)d_in[4];
    // d_in[5] = bc: unused — BatchNorm cancels a per-feature constant shift
    const float* gamma = (const float*)d_in[6];
    const float* beta  = (const float*)d_in[7];
    const float* W1    = (const float*)d_in[8];
    const float* b1    = (const float*)d_in[9];
    const float* W2    = (const float*)d_in[10];
    const float* b2    = (const float*)d_in[11];
    float* out = (float*)d_out;

    char* wsb = (char*)d_ws;
    size_t off = 0;
    auto alloc = [&](size_t bytes) -> char* {
        char* p = wsb + off;
        off = (off + bytes + 255) & ~(size_t)255;
        return p;
    };
    int*   hist    = (int*)alloc(N_NODES * 4);
    int*   incl    = (int*)alloc(N_NODES * 4);
    int*   part    = (int*)alloc(64 * 4);
    int*   starts  = (int*)alloc((N_NODES + 1) * 4);
    int*   cursor  = (int*)alloc(N_NODES * 4);
    int*   csr     = (int*)alloc(N_EDGES * 4);
    float* dis     = (float*)alloc(N_NODES * 4);
    float* h       = (float*)alloc((size_t)N_NODES * HID * 4);
    float* hws     = (float*)alloc((size_t)N_NODES * HWS_LD * 4);
    float* agg     = (float*)alloc((size_t)N_NODES * HID * 4);
    float* partial = (float*)alloc((size_t)NSTAT * 2 * HID * 4);
    float* AB      = (float*)alloc(2 * HID * 4);
    float* hg      = (float*)alloc((size_t)N_GRAPHS * HID * 4);

    const int NB_SCAN = (N_NODES + 1023) / 1024;  // 49
    const int NB_GEMM = (N_NODES + BR - 1) / BR;  // 1563

    // CSR build (reused across all layers)
    hipMemsetAsync(hist, 0, N_NODES * 4, stream);
    k_hist<<<(N_EDGES + 255) / 256, 256, 0, stream>>>(ecol, hist);
    k_scan1<<<NB_SCAN, 1024, 0, stream>>>(hist, incl, part);
    k_scan2<<<1, 64, 0, stream>>>(part, NB_SCAN);
    k_scan3<<<NB_SCAN, 1024, 0, stream>>>(incl, hist, part, starts, cursor, dis);
    k_fill<<<(N_EDGES + 255) / 256, 256, 0, stream>>>(erow, ecol, cursor, csr);

    for (int l = 0; l < N_LAYERS; l++) {
        const float* Wl = Wc + (size_t)l * HID * HID;
        if (l == 0)
            k_gemm_fused<0><<<NB_GEMM, 256, 0, stream>>>(Wl, dis, x, emb, agg, AB, h, hws);
        else
            k_gemm_fused<1><<<NB_GEMM, 256, 0, stream>>>(Wl, dis, x, emb, agg, AB, h, hws);
        k_agg<<<(N_NODES + 3) / 4, 256, 0, stream>>>(hws, starts, csr, dis, agg);
        k_bnstat<<<NSTAT, 192, 0, stream>>>(agg, partial);
        k_bncoef<<<1, 192, 0, stream>>>(partial, gamma + l * HID, beta + l * HID, AB);
    }

    k_pool<<<N_GRAPHS, 192, 0, stream>>>(agg, h, AB, batch, hg);
    k_mlp<<<N_GRAPHS, 128, 0, stream>>>(hg, W1, b1, W2, b2, out);
}

// Round 4
// 866.206 us; speedup vs baseline: 1.4475x; 1.4475x over previous
//
#include <hip/hip_runtime.h>

#define N_NODES  50000
#define N_EDGES  500000
#define N_GRAPHS 2000
#define HID      145
#define HID2     72
#define N_LAYERS 4
#define EPS      1e-5f
#define HWS_LD   160   // padded row stride for gather target: 640B = 5 aligned 128B lines
#define BR       64    // rows per GEMM block
#define NC       19    // cols per wave chunk (8 waves: c0 = w*18, 1-col overlap, covers 145)
#define NSTAT    256   // bnstat partial blocks

// ---------------- CSR build ----------------

__global__ void k_hist(const int* __restrict__ col, int* __restrict__ hist) {
    int i = blockIdx.x * 256 + threadIdx.x;
    if (i < N_EDGES) atomicAdd(&hist[col[i]], 1);
}

__global__ void k_scan1(const int* __restrict__ cnt, int* __restrict__ incl,
                        int* __restrict__ part) {
    __shared__ int s[1024];
    int i = blockIdx.x * 1024 + threadIdx.x;
    int v = (i < N_NODES) ? cnt[i] : 0;
    s[threadIdx.x] = v;
    __syncthreads();
    for (int d = 1; d < 1024; d <<= 1) {
        int t = (threadIdx.x >= d) ? s[threadIdx.x - d] : 0;
        __syncthreads();
        s[threadIdx.x] += t;
        __syncthreads();
    }
    if (i < N_NODES) incl[i] = s[threadIdx.x];
    if (threadIdx.x == 1023) part[blockIdx.x] = s[1023];
}

__global__ void k_scan2(int* part, int nb) {
    if (threadIdx.x == 0 && blockIdx.x == 0) {
        int acc = 0;
        for (int b = 0; b < nb; b++) { int t = part[b]; part[b] = acc; acc += t; }
    }
}

__global__ void k_scan3(const int* __restrict__ incl, const int* __restrict__ cnt,
                        const int* __restrict__ part, int* __restrict__ starts,
                        int* __restrict__ cursor, float* __restrict__ dis) {
    int i = blockIdx.x * 1024 + threadIdx.x;
    if (i < N_NODES) {
        int st = incl[i] - cnt[i] + part[blockIdx.x];
        starts[i] = st;
        cursor[i] = st;
        dis[i] = rsqrtf((float)(cnt[i] + 1));  // +1 self loop
    }
    if (i == 0) starts[N_NODES] = N_EDGES;
}

__global__ void k_fill(const int* __restrict__ rowv, const int* __restrict__ colv,
                       int* __restrict__ cursor, int* __restrict__ csr) {
    int e = blockIdx.x * 256 + threadIdx.x;
    if (e < N_EDGES) {
        int c = colv[e];
        int p = atomicAdd(&cursor[c], 1);
        csr[p] = rowv[e];
    }
}

// ---------------- fused (BN-apply | embed) + GEMM ----------------
// Phase 1: h_new = relu(A*agg+B) + h_old (in place, MODE 1) or emb[x] (MODE 0),
//          written to global h and LDS tile (stride HID=145; 145 mod 32 = 17 odd
//          -> phase-2 column reads conflict-free / 2-way).
// Phase 2: 8 waves; wave w owns col chunk [18w, 18w+19) (wave-uniform -> W via
//          s_load), lane = row. Overlap col duplicated, bit-identical. Epilogue
//          scales by dis -> hws.

template <int MODE>
__global__ __launch_bounds__(512, 6) void k_gemm_fused(
    const float* __restrict__ Wl, const float* __restrict__ dis,
    const int* __restrict__ x, const float* __restrict__ emb,
    const float* __restrict__ agg, const float* __restrict__ AB,
    float* __restrict__ h, float* __restrict__ hws) {
    __shared__ float tile[BR * HID];
    __shared__ float sA[HID], sB[HID];
    int t = threadIdx.x;
    int rbase = blockIdx.x * BR;
    if (MODE == 1 && t < HID) { sA[t] = AB[t]; sB[t] = AB[HID + t]; }
    __syncthreads();
    for (int e = t; e < BR * HID; e += 512) {
        int r = e / HID;
        int f = e - r * HID;
        int gr = rbase + r;
        float v = 0.f;
        if (gr < N_NODES) {
            size_t idx = (size_t)gr * HID + f;
            if (MODE == 0) {
                v = emb[x[gr] * HID + f];
            } else {
                v = fmaf(sA[f], agg[idx], sB[f]);
                v = fmaxf(v, 0.f) + h[idx];
            }
            h[idx] = v;
        }
        tile[e] = v;
    }
    __syncthreads();
    int lane = t & 63;
    int c0 = __builtin_amdgcn_readfirstlane((t >> 6) * 18);  // wave-uniform chunk base
    int gr = rbase + lane;
    float acc[NC];
#pragma unroll
    for (int c = 0; c < NC; c++) acc[c] = 0.f;
    const float* tr = tile + lane * HID;
    const float* wp = Wl + c0;
    for (int k = 0; k < HID; k++) {
        float a = tr[k];
        const float* wr = wp + k * HID;
#pragma unroll
        for (int c = 0; c < NC; c++) acc[c] = fmaf(a, wr[c], acc[c]);
    }
    if (gr < N_NODES) {
        float d = dis[gr];
        float* o = hws + (size_t)gr * HWS_LD + c0;
#pragma unroll
        for (int c = 0; c < NC; c++) o[c] = acc[c] * d;
    }
}

// ---------------- aggregate: agg[i] = dis[i] * (sum_{src in N(i)} hws[src] + hws[i])
// one wave per node; fully-predicated 4-wide edge loop (12 row-loads in flight).

__global__ __launch_bounds__(256) void k_agg(const float* __restrict__ hws,
                                             const int* __restrict__ starts,
                                             const int* __restrict__ csr,
                                             const float* __restrict__ dis,
                                             float* __restrict__ agg) {
    int wave = threadIdx.x >> 6;
    int lane = threadIdx.x & 63;
    int i = blockIdx.x * 4 + wave;
    if (i >= N_NODES) return;
    int s = starts[i], e = starts[i + 1];
    int f0 = lane, f1 = lane + 64, f2 = lane + 128;
    bool p2 = f2 < HID;
    const float* self = hws + (size_t)i * HWS_LD;
    float a0 = self[f0];
    float a1 = self[f1];
    float a2 = p2 ? self[f2] : 0.f;
    int last = e - 1;
    for (int j = s; j < e; j += 4) {
        int j1 = j + 1 < e ? j + 1 : last;
        int j2 = j + 2 < e ? j + 2 : last;
        int j3 = j + 3 < e ? j + 3 : last;
        int s0 = csr[j], s1 = csr[j1], s2 = csr[j2], s3 = csr[j3];
        const float* q0 = hws + (size_t)s0 * HWS_LD;
        const float* q1 = hws + (size_t)s1 * HWS_LD;
        const float* q2 = hws + (size_t)s2 * HWS_LD;
        const float* q3 = hws + (size_t)s3 * HWS_LD;
        float m1 = (j + 1 < e) ? 1.f : 0.f;
        float m2 = (j + 2 < e) ? 1.f : 0.f;
        float m3 = (j + 3 < e) ? 1.f : 0.f;
        a0 += q0[f0] + m1 * q1[f0] + m2 * q2[f0] + m3 * q3[f0];
        a1 += q0[f1] + m1 * q1[f1] + m2 * q2[f1] + m3 * q3[f1];
        if (p2) a2 += q0[f2] + m1 * q1[f2] + m2 * q2[f2] + m3 * q3[f2];
    }
    float di = dis[i];
    float* o = agg + (size_t)i * HID;
    o[f0] = a0 * di;
    o[f1] = a1 * di;
    if (p2) o[f2] = a2 * di;
}

// ---------------- BatchNorm stats ----------------

__global__ __launch_bounds__(192) void k_bnstat(const float* __restrict__ agg,
                                                float* __restrict__ partial) {
    int t = threadIdx.x;
    if (t >= HID) return;
    float s = 0.f, q = 0.f;
    for (int r = blockIdx.x; r < N_NODES; r += NSTAT) {
        float v = agg[(size_t)r * HID + t];
        s += v;
        q = fmaf(v, v, q);
    }
    partial[blockIdx.x * (2 * HID) + t] = s;
    partial[blockIdx.x * (2 * HID) + HID + t] = q;
}

__global__ __launch_bounds__(192) void k_bncoef(const float* __restrict__ partial,
                                                const float* __restrict__ gamma,
                                                const float* __restrict__ beta,
                                                float* __restrict__ AB) {
    int f = threadIdx.x;
    if (f >= HID) return;
    float s = 0.f, q = 0.f;
    for (int b = 0; b < NSTAT; b++) {
        s += partial[b * (2 * HID) + f];
        q += partial[b * (2 * HID) + HID + f];
    }
    const float inv = 1.f / (float)N_NODES;
    float mu = s * inv;
    float var = q * inv - mu * mu;
    float a = gamma[f] * rsqrtf(var + EPS);
    AB[f] = a;
    AB[HID + f] = beta[f] - mu * a;
}

// ---------------- pool (fused with layer-3 BN apply) + MLP ----------------

__global__ __launch_bounds__(192) void k_pool(const float* __restrict__ agg,
                                              const float* __restrict__ h,
                                              const float* __restrict__ AB,
                                              const int* __restrict__ batch,
                                              float* __restrict__ hg) {
    int g = blockIdx.x;
    int lo = 0, hi = N_NODES;
    while (lo < hi) { int m = (lo + hi) >> 1; if (batch[m] < g) lo = m + 1; else hi = m; }
    int s = lo;
    hi = N_NODES;
    while (lo < hi) { int m = (lo + hi) >> 1; if (batch[m] < g + 1) lo = m + 1; else hi = m; }
    int e = lo;
    int f = threadIdx.x;
    if (f >= HID) return;
    float A = AB[f], B = AB[HID + f];
    float acc = 0.f;
    for (int n = s; n < e; n++) {
        size_t idx = (size_t)n * HID + f;
        float v = fmaf(A, agg[idx], B);
        acc += fmaxf(v, 0.f) + h[idx];
    }
    hg[g * HID + f] = acc / fmaxf((float)(e - s), 1.f);
}

__global__ __launch_bounds__(128) void k_mlp(const float* __restrict__ hg,
                                             const float* __restrict__ W1,
                                             const float* __restrict__ b1,
                                             const float* __restrict__ W2,
                                             const float* __restrict__ b2,
                                             float* __restrict__ out) {
    int g = blockIdx.x;
    int t = threadIdx.x;
    float v = 0.f;
    if (t < HID2) {
        float s = b1[t];
        const float* hgr = hg + g * HID;
        for (int k = 0; k < HID; k++) s = fmaf(hgr[k], W1[k * HID2 + t], s);
        v = fmaxf(s, 0.f) * W2[t];
    }
    __shared__ float red[128];
    red[t] = v;
    __syncthreads();
    for (int d = 64; d > 0; d >>= 1) {
        if (t < d) red[t] += red[t + d];
        __syncthreads();
    }
    if (t == 0) out[g] = red[0] + b2[0];
}

// ---------------- host launch ----------------

extern "C" void kernel_launch(void* const* d_in, const int* in_sizes, int n_in,
                              void* d_out, int out_size, void* d_ws, size_t ws_size,
                              hipStream_t stream) {
    const int*   x     = (const int*)d_in[0];
    const int*   erow  = (const int*)d_in[1];
    const int*   ecol  = erow + N_EDGES;
    const int*   batch = (const int*)d_in[2];
    const float* emb   = (const float*)d_in[3];
    const float* Wc    = (const float*)d_in[4];
    // d_in[5] = bc: unused — BatchNorm cancels a per-feature constant shift
    const float* gamma = (const float*)d_in[6];
    const float* beta  = (const float*)d_in[7];
    const float* W1    = (const float*)d_in[8];
    const float* b1    = (const float*)d_in[9];
    const float* W2    = (const float*)d_in[10];
    const float* b2    = (const float*)d_in[11];
    float* out = (float*)d_out;

    char* wsb = (char*)d_ws;
    size_t off = 0;
    auto alloc = [&](size_t bytes) -> char* {
        char* p = wsb + off;
        off = (off + bytes + 255) & ~(size_t)255;
        return p;
    };
    int*   hist    = (int*)alloc(N_NODES * 4);
    int*   incl    = (int*)alloc(N_NODES * 4);
    int*   part    = (int*)alloc(64 * 4);
    int*   starts  = (int*)alloc((N_NODES + 1) * 4);
    int*   cursor  = (int*)alloc(N_NODES * 4);
    int*   csr     = (int*)alloc(N_EDGES * 4);
    float* dis     = (float*)alloc(N_NODES * 4);
    float* h       = (float*)alloc((size_t)N_NODES * HID * 4);
    float* hws     = (float*)alloc((size_t)N_NODES * HWS_LD * 4);
    float* agg     = (float*)alloc((size_t)N_NODES * HID * 4);
    float* partial = (float*)alloc((size_t)NSTAT * 2 * HID * 4);
    float* AB      = (float*)alloc(2 * HID * 4);
    float* hg      = (float*)alloc((size_t)N_GRAPHS * HID * 4);

    const int NB_SCAN = (N_NODES + 1023) / 1024;  // 49
    const int NB_GEMM = (N_NODES + BR - 1) / BR;  // 782

    // CSR build (reused across all layers)
    hipMemsetAsync(hist, 0, N_NODES * 4, stream);
    k_hist<<<(N_EDGES + 255) / 256, 256, 0, stream>>>(ecol, hist);
    k_scan1<<<NB_SCAN, 1024, 0, stream>>>(hist, incl, part);
    k_scan2<<<1, 64, 0, stream>>>(part, NB_SCAN);
    k_scan3<<<NB_SCAN, 1024, 0, stream>>>(incl, hist, part, starts, cursor, dis);
    k_fill<<<(N_EDGES + 255) / 256, 256, 0, stream>>>(erow, ecol, cursor, csr);

    for (int l = 0; l < N_LAYERS; l++) {
        const float* Wl = Wc + (size_t)l * HID * HID;
        if (l == 0)
            k_gemm_fused<0><<<NB_GEMM, 512, 0, stream>>>(Wl, dis, x, emb, agg, AB, h, hws);
        else
            k_gemm_fused<1><<<NB_GEMM, 512, 0, stream>>>(Wl, dis, x, emb, agg, AB, h, hws);
        k_agg<<<(N_NODES + 3) / 4, 256, 0, stream>>>(hws, starts, csr, dis, agg);
        k_bnstat<<<NSTAT, 192, 0, stream>>>(agg, partial);
        k_bncoef<<<1, 192, 0, stream>>>(partial, gamma + l * HID, beta + l * HID, AB);
    }

    k_pool<<<N_GRAPHS, 192, 0, stream>>>(agg, h, AB, batch, hg);
    k_mlp<<<N_GRAPHS, 128, 0, stream>>>(hg, W1, b1, W2, b2, out);
}

// Round 5
// 754.524 us; speedup vs baseline: 1.6617x; 1.1480x over previous
//
#include <hip/hip_runtime.h>

#define N_NODES  50000
#define N_EDGES  500000
#define N_GRAPHS 2000
#define HID      145
#define HID2     72
#define N_LAYERS 4
#define EPS      1e-5f
#define HWS_LD   160   // padded row stride for gather target: 640B = 5 aligned 128B lines
#define BR       64    // rows per GEMM block
#define TSB      168   // bf16 tile stride (shorts): 336B rows -> b128 frag reads 2-way (free)
#define NSTAT    256   // bnstat partial blocks

typedef __attribute__((ext_vector_type(8))) short bf16x8;
typedef __attribute__((ext_vector_type(4))) float f32x4;

static __device__ __forceinline__ unsigned short f32_to_bf16(float f) {
    unsigned int u = __float_as_uint(f);
    unsigned int r = (u + 0x7FFF + ((u >> 16) & 1)) >> 16;  // RNE; data has no NaN
    return (unsigned short)r;
}
static __device__ __forceinline__ float bf16hi_to_f32(unsigned short h) {
    return __uint_as_float((unsigned int)h << 16);
}

// ---------------- CSR build ----------------

__global__ void k_hist(const int* __restrict__ col, int* __restrict__ hist) {
    int i = blockIdx.x * 256 + threadIdx.x;
    if (i < N_EDGES) atomicAdd(&hist[col[i]], 1);
}

__global__ void k_scan1(const int* __restrict__ cnt, int* __restrict__ incl,
                        int* __restrict__ part) {
    __shared__ int s[1024];
    int i = blockIdx.x * 1024 + threadIdx.x;
    int v = (i < N_NODES) ? cnt[i] : 0;
    s[threadIdx.x] = v;
    __syncthreads();
    for (int d = 1; d < 1024; d <<= 1) {
        int t = (threadIdx.x >= d) ? s[threadIdx.x - d] : 0;
        __syncthreads();
        s[threadIdx.x] += t;
        __syncthreads();
    }
    if (i < N_NODES) incl[i] = s[threadIdx.x];
    if (threadIdx.x == 1023) part[blockIdx.x] = s[1023];
}

__global__ void k_scan2(int* part, int nb) {
    if (threadIdx.x == 0 && blockIdx.x == 0) {
        int acc = 0;
        for (int b = 0; b < nb; b++) { int t = part[b]; part[b] = acc; acc += t; }
    }
}

__global__ void k_scan3(const int* __restrict__ incl, const int* __restrict__ cnt,
                        const int* __restrict__ part, int* __restrict__ starts,
                        int* __restrict__ cursor, float* __restrict__ dis) {
    int i = blockIdx.x * 1024 + threadIdx.x;
    if (i < N_NODES) {
        int st = incl[i] - cnt[i] + part[blockIdx.x];
        starts[i] = st;
        cursor[i] = st;
        dis[i] = rsqrtf((float)(cnt[i] + 1));  // +1 self loop
    }
    if (i == 0) starts[N_NODES] = N_EDGES;
}

__global__ void k_fill(const int* __restrict__ rowv, const int* __restrict__ colv,
                       int* __restrict__ cursor, int* __restrict__ csr) {
    int e = blockIdx.x * 256 + threadIdx.x;
    if (e < N_EDGES) {
        int c = colv[e];
        int p = atomicAdd(&cursor[c], 1);
        csr[p] = rowv[e];
    }
}

// ---------------- W -> fragment-ordered split-bf16 planes (once per call) ----
// Frag fid = layer*50 + kc*10 + ct: 1024 shorts = [hi 512 | lo 512];
// lane l, elem j: B[k = kc*32+(l>>4)*8+j][c = ct*16+(l&15)], zero-padded.

__global__ void k_wfrag(const float* __restrict__ Wc, short* __restrict__ Wfrag) {
    int fid = blockIdx.x;                 // 0..199
    int layer = fid / 50, rem = fid - layer * 50;
    int kc = rem / 10, ct = rem - kc * 10;
    int l = threadIdx.x;                  // 0..63
    const float* Wl = Wc + (size_t)layer * HID * HID;
    short* base = Wfrag + (size_t)fid * 1024 + l * 8;
#pragma unroll
    for (int j = 0; j < 8; j++) {
        int k = kc * 32 + (l >> 4) * 8 + j;
        int c = ct * 16 + (l & 15);
        float v = (k < HID && c < HID) ? Wl[k * HID + c] : 0.f;
        unsigned short hb = f32_to_bf16(v);
        unsigned short lb = f32_to_bf16(v - bf16hi_to_f32(hb));
        base[j] = (short)hb;
        base[512 + j] = (short)lb;
    }
}

// ---------------- fused (BN-apply | embed) + MFMA GEMM ----------------
// Phase 1: v = relu(A*agg+B)+h_old (MODE 1) or emb[x] (MODE 0); write h global
//          and split-bf16 LDS planes (v = hi + lo exactly to ~2^-17).
// Phase 2: 8 waves: rt = w&3 (16-row tile), col-half = (w>>2)*5 (5 x 16-col tiles);
//          K = 5 chunks of 32; D ~= Ah*Bh + Ah*Bl + Al*Bh (3 MFMAs, error ~2^-17).
// Epilogue scales by dis -> hws (padded cols carry zeros from zero-padded W frags).

#define MFMA(a, b, c) __builtin_amdgcn_mfma_f32_16x16x32_bf16(a, b, c, 0, 0, 0)

template <int MODE>
__global__ __launch_bounds__(512, 6) void k_gemm_fused(
    const short* __restrict__ wfb, const float* __restrict__ dis,
    const int* __restrict__ x, const float* __restrict__ emb,
    const float* __restrict__ agg, const float* __restrict__ AB,
    float* __restrict__ h, float* __restrict__ hws) {
    __shared__ short tileH[BR * TSB];
    __shared__ short tileL[BR * TSB];
    __shared__ float sA[HID], sB[HID];
    int t = threadIdx.x;
    int rbase = blockIdx.x * BR;
    if (MODE == 1 && t < HID) { sA[t] = AB[t]; sB[t] = AB[HID + t]; }
    __syncthreads();
    for (int e2 = t; e2 < BR * HID; e2 += 512) {
        int r = e2 / HID;
        int f = e2 - r * HID;
        int gr = rbase + r;
        float v = 0.f;
        if (gr < N_NODES) {
            size_t idx = (size_t)gr * HID + f;
            if (MODE == 0) {
                v = emb[x[gr] * HID + f];
            } else {
                v = fmaf(sA[f], agg[idx], sB[f]);
                v = fmaxf(v, 0.f) + h[idx];
            }
            h[idx] = v;
        }
        unsigned short hb = f32_to_bf16(v);
        unsigned short lb = f32_to_bf16(v - bf16hi_to_f32(hb));
        tileH[r * TSB + f] = (short)hb;
        tileL[r * TSB + f] = (short)lb;
    }
    // zero K-padding cols [145,160)
    for (int idx = t; idx < BR * 15; idx += 512) {
        int r = idx / 15;
        int f = HID + (idx - r * 15);
        tileH[r * TSB + f] = 0;
        tileL[r * TSB + f] = 0;
    }
    __syncthreads();

    int w = t >> 6, l = t & 63;
    int rt = w & 3;
    int c5 = (w >> 2) * 5;                 // col-tile base: 0 or 5
    int arow = rt * 16 + (l & 15);
    int kgrp = (l >> 4) * 8;
    f32x4 acc0 = {}, acc1 = {}, acc2 = {}, acc3 = {}, acc4 = {};
#pragma unroll
    for (int kc = 0; kc < 5; kc++) {
        int ai = arow * TSB + kc * 32 + kgrp;
        bf16x8 ah = *(const bf16x8*)&tileH[ai];
        bf16x8 al = *(const bf16x8*)&tileL[ai];
        const short* p = wfb + (size_t)(kc * 10 + c5) * 1024 + l * 8;
        bf16x8 bh, bl;
#define STEP(ACC, CI)                                                      \
        bh = *(const bf16x8*)(p + (CI) * 1024);                            \
        bl = *(const bf16x8*)(p + (CI) * 1024 + 512);                      \
        ACC = MFMA(ah, bh, ACC);                                           \
        ACC = MFMA(ah, bl, ACC);                                           \
        ACC = MFMA(al, bh, ACC);
        STEP(acc0, 0) STEP(acc1, 1) STEP(acc2, 2) STEP(acc3, 3) STEP(acc4, 4)
#undef STEP
    }
    int rb4 = rbase + rt * 16 + (l >> 4) * 4;
    f32x4 d4 = *(const f32x4*)(dis + rb4);  // dis alloc padded; OOB lanes guarded below
    int colb = c5 * 16 + (l & 15);
#pragma unroll
    for (int r_ = 0; r_ < 4; r_++) {
        int gr = rb4 + r_;
        if (gr < N_NODES) {
            float dd = d4[r_];
            float* row = hws + (size_t)gr * HWS_LD + colb;
            row[0]  = acc0[r_] * dd;
            row[16] = acc1[r_] * dd;
            row[32] = acc2[r_] * dd;
            row[48] = acc3[r_] * dd;
            row[64] = acc4[r_] * dd;
        }
    }
}

// ---------------- aggregate: agg[i] = dis[i] * (sum_{src in N(i)} hws[src] + hws[i])
// one wave per node; fully-predicated 8-wide edge loop (24 row-loads in flight).

__global__ __launch_bounds__(256) void k_agg(const float* __restrict__ hws,
                                             const int* __restrict__ starts,
                                             const int* __restrict__ csr,
                                             const float* __restrict__ dis,
                                             float* __restrict__ agg) {
    int wave = threadIdx.x >> 6;
    int lane = threadIdx.x & 63;
    int i = blockIdx.x * 4 + wave;
    if (i >= N_NODES) return;
    int s = starts[i], e = starts[i + 1];
    int f0 = lane, f1 = lane + 64, f2 = lane + 128;
    bool p2 = f2 < HID;
    const float* self = hws + (size_t)i * HWS_LD;
    float a0 = self[f0];
    float a1 = self[f1];
    float a2 = p2 ? self[f2] : 0.f;
    int last = e - 1;
    for (int j = s; j < e; j += 8) {
        int j1 = j + 1 < e ? j + 1 : last;
        int j2 = j + 2 < e ? j + 2 : last;
        int j3 = j + 3 < e ? j + 3 : last;
        int j4 = j + 4 < e ? j + 4 : last;
        int j5 = j + 5 < e ? j + 5 : last;
        int j6 = j + 6 < e ? j + 6 : last;
        int j7 = j + 7 < e ? j + 7 : last;
        const float* q0 = hws + (size_t)csr[j]  * HWS_LD;
        const float* q1 = hws + (size_t)csr[j1] * HWS_LD;
        const float* q2 = hws + (size_t)csr[j2] * HWS_LD;
        const float* q3 = hws + (size_t)csr[j3] * HWS_LD;
        const float* q4 = hws + (size_t)csr[j4] * HWS_LD;
        const float* q5 = hws + (size_t)csr[j5] * HWS_LD;
        const float* q6 = hws + (size_t)csr[j6] * HWS_LD;
        const float* q7 = hws + (size_t)csr[j7] * HWS_LD;
        float m1 = (j + 1 < e) ? 1.f : 0.f;
        float m2 = (j + 2 < e) ? 1.f : 0.f;
        float m3 = (j + 3 < e) ? 1.f : 0.f;
        float m4 = (j + 4 < e) ? 1.f : 0.f;
        float m5 = (j + 5 < e) ? 1.f : 0.f;
        float m6 = (j + 6 < e) ? 1.f : 0.f;
        float m7 = (j + 7 < e) ? 1.f : 0.f;
        a0 += ((q0[f0] + m1 * q1[f0]) + (m2 * q2[f0] + m3 * q3[f0])) +
              ((m4 * q4[f0] + m5 * q5[f0]) + (m6 * q6[f0] + m7 * q7[f0]));
        a1 += ((q0[f1] + m1 * q1[f1]) + (m2 * q2[f1] + m3 * q3[f1])) +
              ((m4 * q4[f1] + m5 * q5[f1]) + (m6 * q6[f1] + m7 * q7[f1]));
        if (p2)
            a2 += ((q0[f2] + m1 * q1[f2]) + (m2 * q2[f2] + m3 * q3[f2])) +
                  ((m4 * q4[f2] + m5 * q5[f2]) + (m6 * q6[f2] + m7 * q7[f2]));
    }
    float di = dis[i];
    float* o = agg + (size_t)i * HID;
    o[f0] = a0 * di;
    o[f1] = a1 * di;
    if (p2) o[f2] = a2 * di;
}

// ---------------- BatchNorm stats ----------------

__global__ __launch_bounds__(192) void k_bnstat(const float* __restrict__ agg,
                                                float* __restrict__ partial) {
    int t = threadIdx.x;
    if (t >= HID) return;
    float s = 0.f, q = 0.f;
    for (int r = blockIdx.x; r < N_NODES; r += NSTAT) {
        float v = agg[(size_t)r * HID + t];
        s += v;
        q = fmaf(v, v, q);
    }
    partial[blockIdx.x * (2 * HID) + t] = s;
    partial[blockIdx.x * (2 * HID) + HID + t] = q;
}

__global__ __launch_bounds__(192) void k_bncoef(const float* __restrict__ partial,
                                                const float* __restrict__ gamma,
                                                const float* __restrict__ beta,
                                                float* __restrict__ AB) {
    int f = threadIdx.x;
    if (f >= HID) return;
    float s = 0.f, q = 0.f;
    for (int b = 0; b < NSTAT; b++) {
        s += partial[b * (2 * HID) + f];
        q += partial[b * (2 * HID) + HID + f];
    }
    const float inv = 1.f / (float)N_NODES;
    float mu = s * inv;
    float var = q * inv - mu * mu;
    float a = gamma[f] * rsqrtf(var + EPS);
    AB[f] = a;
    AB[HID + f] = beta[f] - mu * a;
}

// ---------------- pool (fused with layer-3 BN apply) + MLP ----------------

__global__ __launch_bounds__(192) void k_pool(const float* __restrict__ agg,
                                              const float* __restrict__ h,
                                              const float* __restrict__ AB,
                                              const int* __restrict__ batch,
                                              float* __restrict__ hg) {
    int g = blockIdx.x;
    int lo = 0, hi = N_NODES;
    while (lo < hi) { int m = (lo + hi) >> 1; if (batch[m] < g) lo = m + 1; else hi = m; }
    int s = lo;
    hi = N_NODES;
    while (lo < hi) { int m = (lo + hi) >> 1; if (batch[m] < g + 1) lo = m + 1; else hi = m; }
    int e = lo;
    int f = threadIdx.x;
    if (f >= HID) return;
    float A = AB[f], B = AB[HID + f];
    float acc = 0.f;
    for (int n = s; n < e; n++) {
        size_t idx = (size_t)n * HID + f;
        float v = fmaf(A, agg[idx], B);
        acc += fmaxf(v, 0.f) + h[idx];
    }
    hg[g * HID + f] = acc / fmaxf((float)(e - s), 1.f);
}

__global__ __launch_bounds__(128) void k_mlp(const float* __restrict__ hg,
                                             const float* __restrict__ W1,
                                             const float* __restrict__ b1,
                                             const float* __restrict__ W2,
                                             const float* __restrict__ b2,
                                             float* __restrict__ out) {
    int g = blockIdx.x;
    int t = threadIdx.x;
    float v = 0.f;
    if (t < HID2) {
        float s = b1[t];
        const float* hgr = hg + g * HID;
        for (int k = 0; k < HID; k++) s = fmaf(hgr[k], W1[k * HID2 + t], s);
        v = fmaxf(s, 0.f) * W2[t];
    }
    __shared__ float red[128];
    red[t] = v;
    __syncthreads();
    for (int d = 64; d > 0; d >>= 1) {
        if (t < d) red[t] += red[t + d];
        __syncthreads();
    }
    if (t == 0) out[g] = red[0] + b2[0];
}

// ---------------- host launch ----------------

extern "C" void kernel_launch(void* const* d_in, const int* in_sizes, int n_in,
                              void* d_out, int out_size, void* d_ws, size_t ws_size,
                              hipStream_t stream) {
    const int*   x     = (const int*)d_in[0];
    const int*   erow  = (const int*)d_in[1];
    const int*   ecol  = erow + N_EDGES;
    const int*   batch = (const int*)d_in[2];
    const float* emb   = (const float*)d_in[3];
    const float* Wc    = (const float*)d_in[4];
    // d_in[5] = bc: unused — BatchNorm cancels a per-feature constant shift
    const float* gamma = (const float*)d_in[6];
    const float* beta  = (const float*)d_in[7];
    const float* W1    = (const float*)d_in[8];
    const float* b1    = (const float*)d_in[9];
    const float* W2    = (const float*)d_in[10];
    const float* b2    = (const float*)d_in[11];
    float* out = (float*)d_out;

    char* wsb = (char*)d_ws;
    size_t off = 0;
    auto alloc = [&](size_t bytes) -> char* {
        char* p = wsb + off;
        off = (off + bytes + 255) & ~(size_t)255;
        return p;
    };
    int*   hist    = (int*)alloc(N_NODES * 4);
    int*   incl    = (int*)alloc(N_NODES * 4);
    int*   part    = (int*)alloc(64 * 4);
    int*   starts  = (int*)alloc((N_NODES + 1) * 4);
    int*   cursor  = (int*)alloc(N_NODES * 4);
    int*   csr     = (int*)alloc(N_EDGES * 4);
    float* dis     = (float*)alloc((N_NODES + 64) * 4);  // padded: epilogue float4 reads
    float* h       = (float*)alloc((size_t)N_NODES * HID * 4);
    float* hws     = (float*)alloc((size_t)N_NODES * HWS_LD * 4);
    float* agg     = (float*)alloc((size_t)N_NODES * HID * 4);
    float* partial = (float*)alloc((size_t)NSTAT * 2 * HID * 4);
    float* AB      = (float*)alloc(2 * HID * 4);
    float* hg      = (float*)alloc((size_t)N_GRAPHS * HID * 4);
    short* Wfrag   = (short*)alloc((size_t)N_LAYERS * 50 * 1024 * 2);

    const int NB_SCAN = (N_NODES + 1023) / 1024;  // 49
    const int NB_GEMM = (N_NODES + BR - 1) / BR;  // 782

    // CSR build (reused across all layers) + W fragment planes
    hipMemsetAsync(hist, 0, N_NODES * 4, stream);
    k_hist<<<(N_EDGES + 255) / 256, 256, 0, stream>>>(ecol, hist);
    k_scan1<<<NB_SCAN, 1024, 0, stream>>>(hist, incl, part);
    k_scan2<<<1, 64, 0, stream>>>(part, NB_SCAN);
    k_scan3<<<NB_SCAN, 1024, 0, stream>>>(incl, hist, part, starts, cursor, dis);
    k_fill<<<(N_EDGES + 255) / 256, 256, 0, stream>>>(erow, ecol, cursor, csr);
    k_wfrag<<<N_LAYERS * 50, 64, 0, stream>>>(Wc, Wfrag);

    for (int l = 0; l < N_LAYERS; l++) {
        const short* wfb = Wfrag + (size_t)l * 50 * 1024;
        if (l == 0)
            k_gemm_fused<0><<<NB_GEMM, 512, 0, stream>>>(wfb, dis, x, emb, agg, AB, h, hws);
        else
            k_gemm_fused<1><<<NB_GEMM, 512, 0, stream>>>(wfb, dis, x, emb, agg, AB, h, hws);
        k_agg<<<(N_NODES + 3) / 4, 256, 0, stream>>>(hws, starts, csr, dis, agg);
        k_bnstat<<<NSTAT, 192, 0, stream>>>(agg, partial);
        k_bncoef<<<1, 192, 0, stream>>>(partial, gamma + l * HID, beta + l * HID, AB);
    }

    k_pool<<<N_GRAPHS, 192, 0, stream>>>(agg, h, AB, batch, hg);
    k_mlp<<<N_GRAPHS, 128, 0, stream>>>(hg, W1, b1, W2, b2, out);
}

// Round 6
// 549.499 us; speedup vs baseline: 2.2817x; 1.3731x over previous
//
#include <hip/hip_runtime.h>

#define N_NODES  50000
#define N_EDGES  500000
#define N_GRAPHS 2000
#define HID      145
#define HID2     72
#define N_LAYERS 4
#define EPS      1e-5f
#define HWS_LD   160   // padded row stride for gather target: 640B = 5 aligned 128B lines
#define BR       64    // rows per GEMM block
#define TSB      168   // bf16 tile stride (shorts): 336B rows -> b128 frag reads 2-way (free)
#define NSTAT    1024  // bnstat partial blocks

typedef __attribute__((ext_vector_type(8))) short bf16x8;
typedef __attribute__((ext_vector_type(4))) float f32x4;

static __device__ __forceinline__ unsigned short f32_to_bf16(float f) {
    unsigned int u = __float_as_uint(f);
    unsigned int r = (u + 0x7FFF + ((u >> 16) & 1)) >> 16;  // RNE; data has no NaN
    return (unsigned short)r;
}
static __device__ __forceinline__ float bf16hi_to_f32(unsigned short h) {
    return __uint_as_float((unsigned int)h << 16);
}

// ---------------- CSR build ----------------

__global__ void k_hist(const int* __restrict__ col, int* __restrict__ hist) {
    int i = blockIdx.x * 256 + threadIdx.x;
    if (i < N_EDGES) atomicAdd(&hist[col[i]], 1);
}

__global__ void k_scan1(const int* __restrict__ cnt, int* __restrict__ incl,
                        int* __restrict__ part) {
    __shared__ int s[1024];
    int i = blockIdx.x * 1024 + threadIdx.x;
    int v = (i < N_NODES) ? cnt[i] : 0;
    s[threadIdx.x] = v;
    __syncthreads();
    for (int d = 1; d < 1024; d <<= 1) {
        int t = (threadIdx.x >= d) ? s[threadIdx.x - d] : 0;
        __syncthreads();
        s[threadIdx.x] += t;
        __syncthreads();
    }
    if (i < N_NODES) incl[i] = s[threadIdx.x];
    if (threadIdx.x == 1023) part[blockIdx.x] = s[1023];
}

__global__ void k_scan2(int* part, int nb) {
    if (threadIdx.x == 0 && blockIdx.x == 0) {
        int acc = 0;
        for (int b = 0; b < nb; b++) { int t = part[b]; part[b] = acc; acc += t; }
    }
}

__global__ void k_scan3(const int* __restrict__ incl, const int* __restrict__ cnt,
                        const int* __restrict__ part, int* __restrict__ starts,
                        int* __restrict__ cursor, float* __restrict__ dis) {
    int i = blockIdx.x * 1024 + threadIdx.x;
    if (i < N_NODES) {
        int st = incl[i] - cnt[i] + part[blockIdx.x];
        starts[i] = st;
        cursor[i] = st;
        dis[i] = rsqrtf((float)(cnt[i] + 1));  // +1 self loop
    }
    if (i == 0) starts[N_NODES] = N_EDGES;
}

__global__ void k_fill(const int* __restrict__ rowv, const int* __restrict__ colv,
                       int* __restrict__ cursor, int* __restrict__ csr) {
    int e = blockIdx.x * 256 + threadIdx.x;
    if (e < N_EDGES) {
        int c = colv[e];
        int p = atomicAdd(&cursor[c], 1);
        csr[p] = rowv[e];
    }
}

// ---------------- W -> fragment-ordered split-bf16 planes (once per call) ----
// Frag fid = layer*50 + kc*10 + ct: 1024 shorts = [hi 512 | lo 512];
// lane l, elem j: B[k = kc*32+(l>>4)*8+j][c = ct*16+(l&15)], zero-padded.

__global__ void k_wfrag(const float* __restrict__ Wc, short* __restrict__ Wfrag) {
    int fid = blockIdx.x;                 // 0..199
    int layer = fid / 50, rem = fid - layer * 50;
    int kc = rem / 10, ct = rem - kc * 10;
    int l = threadIdx.x;                  // 0..63
    const float* Wl = Wc + (size_t)layer * HID * HID;
    short* base = Wfrag + (size_t)fid * 1024 + l * 8;
#pragma unroll
    for (int j = 0; j < 8; j++) {
        int k = kc * 32 + (l >> 4) * 8 + j;
        int c = ct * 16 + (l & 15);
        float v = (k < HID && c < HID) ? Wl[k * HID + c] : 0.f;
        unsigned short hb = f32_to_bf16(v);
        unsigned short lb = f32_to_bf16(v - bf16hi_to_f32(hb));
        base[j] = (short)hb;
        base[512 + j] = (short)lb;
    }
}

// ---------------- fused (BN-apply | embed) + MFMA GEMM ----------------
// Phase 1: v = relu(A*agg+B)+h_old (MODE 1) or emb[x] (MODE 0); write h global
//          and split-bf16 LDS planes (v = hi + lo exactly to ~2^-17).
// Phase 2: 8 waves: rt = w&3 (16-row tile), col-half = (w>>2)*5 (5 x 16-col tiles);
//          K = 5 chunks of 32; D ~= Ah*Bh + Ah*Bl + Al*Bh (3 MFMAs, error ~2^-17).
// Epilogue scales by dis -> hws (padded cols carry zeros from zero-padded W frags).

#define MFMA(a, b, c) __builtin_amdgcn_mfma_f32_16x16x32_bf16(a, b, c, 0, 0, 0)

template <int MODE>
__global__ __launch_bounds__(512, 6) void k_gemm_fused(
    const short* __restrict__ wfb, const float* __restrict__ dis,
    const int* __restrict__ x, const float* __restrict__ emb,
    const float* __restrict__ agg, const float* __restrict__ AB,
    float* __restrict__ h, float* __restrict__ hws) {
    __shared__ short tileH[BR * TSB];
    __shared__ short tileL[BR * TSB];
    __shared__ float sA[HID], sB[HID];
    int t = threadIdx.x;
    int rbase = blockIdx.x * BR;
    if (MODE == 1 && t < HID) { sA[t] = AB[t]; sB[t] = AB[HID + t]; }
    __syncthreads();
    for (int e2 = t; e2 < BR * HID; e2 += 512) {
        int r = e2 / HID;
        int f = e2 - r * HID;
        int gr = rbase + r;
        float v = 0.f;
        if (gr < N_NODES) {
            size_t idx = (size_t)gr * HID + f;
            if (MODE == 0) {
                v = emb[x[gr] * HID + f];
            } else {
                v = fmaf(sA[f], agg[idx], sB[f]);
                v = fmaxf(v, 0.f) + h[idx];
            }
            h[idx] = v;
        }
        unsigned short hb = f32_to_bf16(v);
        unsigned short lb = f32_to_bf16(v - bf16hi_to_f32(hb));
        tileH[r * TSB + f] = (short)hb;
        tileL[r * TSB + f] = (short)lb;
    }
    // zero K-padding cols [145,160)
    for (int idx = t; idx < BR * 15; idx += 512) {
        int r = idx / 15;
        int f = HID + (idx - r * 15);
        tileH[r * TSB + f] = 0;
        tileL[r * TSB + f] = 0;
    }
    __syncthreads();

    int w = t >> 6, l = t & 63;
    int rt = w & 3;
    int c5 = (w >> 2) * 5;                 // col-tile base: 0 or 5
    int arow = rt * 16 + (l & 15);
    int kgrp = (l >> 4) * 8;
    f32x4 acc0 = {}, acc1 = {}, acc2 = {}, acc3 = {}, acc4 = {};
#pragma unroll
    for (int kc = 0; kc < 5; kc++) {
        int ai = arow * TSB + kc * 32 + kgrp;
        bf16x8 ah = *(const bf16x8*)&tileH[ai];
        bf16x8 al = *(const bf16x8*)&tileL[ai];
        const short* p = wfb + (size_t)(kc * 10 + c5) * 1024 + l * 8;
        bf16x8 bh, bl;
#define STEP(ACC, CI)                                                      \
        bh = *(const bf16x8*)(p + (CI) * 1024);                            \
        bl = *(const bf16x8*)(p + (CI) * 1024 + 512);                      \
        ACC = MFMA(ah, bh, ACC);                                           \
        ACC = MFMA(ah, bl, ACC);                                           \
        ACC = MFMA(al, bh, ACC);
        STEP(acc0, 0) STEP(acc1, 1) STEP(acc2, 2) STEP(acc3, 3) STEP(acc4, 4)
#undef STEP
    }
    int rb4 = rbase + rt * 16 + (l >> 4) * 4;
    f32x4 d4 = *(const f32x4*)(dis + rb4);  // dis alloc padded; OOB lanes guarded below
    int colb = c5 * 16 + (l & 15);
#pragma unroll
    for (int r_ = 0; r_ < 4; r_++) {
        int gr = rb4 + r_;
        if (gr < N_NODES) {
            float dd = d4[r_];
            float* row = hws + (size_t)gr * HWS_LD + colb;
            row[0]  = acc0[r_] * dd;
            row[16] = acc1[r_] * dd;
            row[32] = acc2[r_] * dd;
            row[48] = acc3[r_] * dd;
            row[64] = acc4[r_] * dd;
        }
    }
}

// ---------------- aggregate: agg[i] = dis[i] * (sum_{src in N(i)} hws[src] + hws[i])
// one wave per node; fully-predicated 8-wide edge loop (24 row-loads in flight).

__global__ __launch_bounds__(256) void k_agg(const float* __restrict__ hws,
                                             const int* __restrict__ starts,
                                             const int* __restrict__ csr,
                                             const float* __restrict__ dis,
                                             float* __restrict__ agg) {
    int wave = threadIdx.x >> 6;
    int lane = threadIdx.x & 63;
    int i = blockIdx.x * 4 + wave;
    if (i >= N_NODES) return;
    int s = starts[i], e = starts[i + 1];
    int f0 = lane, f1 = lane + 64, f2 = lane + 128;
    bool p2 = f2 < HID;
    const float* self = hws + (size_t)i * HWS_LD;
    float a0 = self[f0];
    float a1 = self[f1];
    float a2 = p2 ? self[f2] : 0.f;
    int last = e - 1;
    for (int j = s; j < e; j += 8) {
        int j1 = j + 1 < e ? j + 1 : last;
        int j2 = j + 2 < e ? j + 2 : last;
        int j3 = j + 3 < e ? j + 3 : last;
        int j4 = j + 4 < e ? j + 4 : last;
        int j5 = j + 5 < e ? j + 5 : last;
        int j6 = j + 6 < e ? j + 6 : last;
        int j7 = j + 7 < e ? j + 7 : last;
        const float* q0 = hws + (size_t)csr[j]  * HWS_LD;
        const float* q1 = hws + (size_t)csr[j1] * HWS_LD;
        const float* q2 = hws + (size_t)csr[j2] * HWS_LD;
        const float* q3 = hws + (size_t)csr[j3] * HWS_LD;
        const float* q4 = hws + (size_t)csr[j4] * HWS_LD;
        const float* q5 = hws + (size_t)csr[j5] * HWS_LD;
        const float* q6 = hws + (size_t)csr[j6] * HWS_LD;
        const float* q7 = hws + (size_t)csr[j7] * HWS_LD;
        float m1 = (j + 1 < e) ? 1.f : 0.f;
        float m2 = (j + 2 < e) ? 1.f : 0.f;
        float m3 = (j + 3 < e) ? 1.f : 0.f;
        float m4 = (j + 4 < e) ? 1.f : 0.f;
        float m5 = (j + 5 < e) ? 1.f : 0.f;
        float m6 = (j + 6 < e) ? 1.f : 0.f;
        float m7 = (j + 7 < e) ? 1.f : 0.f;
        a0 += ((q0[f0] + m1 * q1[f0]) + (m2 * q2[f0] + m3 * q3[f0])) +
              ((m4 * q4[f0] + m5 * q5[f0]) + (m6 * q6[f0] + m7 * q7[f0]));
        a1 += ((q0[f1] + m1 * q1[f1]) + (m2 * q2[f1] + m3 * q3[f1])) +
              ((m4 * q4[f1] + m5 * q5[f1]) + (m6 * q6[f1] + m7 * q7[f1]));
        if (p2)
            a2 += ((q0[f2] + m1 * q1[f2]) + (m2 * q2[f2] + m3 * q3[f2])) +
                  ((m4 * q4[f2] + m5 * q5[f2]) + (m6 * q6[f2] + m7 * q7[f2]));
    }
    float di = dis[i];
    float* o = agg + (size_t)i * HID;
    o[f0] = a0 * di;
    o[f1] = a1 * di;
    if (p2) o[f2] = a2 * di;
}

// ---------------- BatchNorm stats ----------------
// NSTAT blocks, unroll-4 rows (4 loads in flight/thread). Partials stored
// transposed [2*HID][NSTAT] so the reducer reads coalesced.

__global__ __launch_bounds__(192) void k_bnstat(const float* __restrict__ agg,
                                                float* __restrict__ partial) {
    int t = threadIdx.x;
    if (t >= HID) return;
    int b = blockIdx.x;
    float s = 0.f, q = 0.f;
    for (int r = b; r < N_NODES; r += 4 * NSTAT) {
        int r1 = r + NSTAT, r2 = r + 2 * NSTAT, r3 = r + 3 * NSTAT;
        float v0 = agg[(size_t)r * HID + t];
        float v1 = (r1 < N_NODES) ? agg[(size_t)r1 * HID + t] : 0.f;
        float v2 = (r2 < N_NODES) ? agg[(size_t)r2 * HID + t] : 0.f;
        float v3 = (r3 < N_NODES) ? agg[(size_t)r3 * HID + t] : 0.f;
        s += (v0 + v1) + (v2 + v3);
        q = fmaf(v0, v0, q);
        q = fmaf(v1, v1, q);
        q = fmaf(v2, v2, q);
        q = fmaf(v3, v3, q);
    }
    partial[(size_t)t * NSTAT + b] = s;
    partial[(size_t)(HID + t) * NSTAT + b] = q;
}

// one wave per feature: reduce sum-row & sq-row (coalesced), butterfly, write A/B.

__global__ __launch_bounds__(256) void k_bncoef(const float* __restrict__ partial,
                                                const float* __restrict__ gamma,
                                                const float* __restrict__ beta,
                                                float* __restrict__ AB) {
    int w = blockIdx.x * 4 + (threadIdx.x >> 6);
    int lane = threadIdx.x & 63;
    if (w >= HID) return;
    const float* ps = partial + (size_t)w * NSTAT;
    const float* pq = partial + (size_t)(HID + w) * NSTAT;
    float s = 0.f, q = 0.f;
#pragma unroll
    for (int b = 0; b < NSTAT / 64; b++) {
        s += ps[b * 64 + lane];
        q += pq[b * 64 + lane];
    }
#pragma unroll
    for (int d = 32; d > 0; d >>= 1) {
        s += __shfl_xor(s, d);
        q += __shfl_xor(q, d);
    }
    if (lane == 0) {
        const float inv = 1.f / (float)N_NODES;
        float mu = s * inv;
        float var = q * inv - mu * mu;
        float a = gamma[w] * rsqrtf(var + EPS);
        AB[w] = a;
        AB[HID + w] = beta[w] - mu * a;
    }
}

// ---------------- pool (fused with layer-3 BN apply) + MLP ----------------

__global__ __launch_bounds__(192) void k_pool(const float* __restrict__ agg,
                                              const float* __restrict__ h,
                                              const float* __restrict__ AB,
                                              const int* __restrict__ batch,
                                              float* __restrict__ hg) {
    int g = blockIdx.x;
    int lo = 0, hi = N_NODES;
    while (lo < hi) { int m = (lo + hi) >> 1; if (batch[m] < g) lo = m + 1; else hi = m; }
    int s = lo;
    hi = N_NODES;
    while (lo < hi) { int m = (lo + hi) >> 1; if (batch[m] < g + 1) lo = m + 1; else hi = m; }
    int e = lo;
    int f = threadIdx.x;
    if (f >= HID) return;
    float A = AB[f], B = AB[HID + f];
    float acc = 0.f;
    for (int n = s; n < e; n++) {
        size_t idx = (size_t)n * HID + f;
        float v = fmaf(A, agg[idx], B);
        acc += fmaxf(v, 0.f) + h[idx];
    }
    hg[g * HID + f] = acc / fmaxf((float)(e - s), 1.f);
}

__global__ __launch_bounds__(128) void k_mlp(const float* __restrict__ hg,
                                             const float* __restrict__ W1,
                                             const float* __restrict__ b1,
                                             const float* __restrict__ W2,
                                             const float* __restrict__ b2,
                                             float* __restrict__ out) {
    int g = blockIdx.x;
    int t = threadIdx.x;
    float v = 0.f;
    if (t < HID2) {
        float s = b1[t];
        const float* hgr = hg + g * HID;
        for (int k = 0; k < HID; k++) s = fmaf(hgr[k], W1[k * HID2 + t], s);
        v = fmaxf(s, 0.f) * W2[t];
    }
    __shared__ float red[128];
    red[t] = v;
    __syncthreads();
    for (int d = 64; d > 0; d >>= 1) {
        if (t < d) red[t] += red[t + d];
        __syncthreads();
    }
    if (t == 0) out[g] = red[0] + b2[0];
}

// ---------------- host launch ----------------

extern "C" void kernel_launch(void* const* d_in, const int* in_sizes, int n_in,
                              void* d_out, int out_size, void* d_ws, size_t ws_size,
                              hipStream_t stream) {
    const int*   x     = (const int*)d_in[0];
    const int*   erow  = (const int*)d_in[1];
    const int*   ecol  = erow + N_EDGES;
    const int*   batch = (const int*)d_in[2];
    const float* emb   = (const float*)d_in[3];
    const float* Wc    = (const float*)d_in[4];
    // d_in[5] = bc: unused — BatchNorm cancels a per-feature constant shift
    const float* gamma = (const float*)d_in[6];
    const float* beta  = (const float*)d_in[7];
    const float* W1    = (const float*)d_in[8];
    const float* b1    = (const float*)d_in[9];
    const float* W2    = (const float*)d_in[10];
    const float* b2    = (const float*)d_in[11];
    float* out = (float*)d_out;

    char* wsb = (char*)d_ws;
    size_t off = 0;
    auto alloc = [&](size_t bytes) -> char* {
        char* p = wsb + off;
        off = (off + bytes + 255) & ~(size_t)255;
        return p;
    };
    int*   hist    = (int*)alloc(N_NODES * 4);
    int*   incl    = (int*)alloc(N_NODES * 4);
    int*   part    = (int*)alloc(64 * 4);
    int*   starts  = (int*)alloc((N_NODES + 1) * 4);
    int*   cursor  = (int*)alloc(N_NODES * 4);
    int*   csr     = (int*)alloc(N_EDGES * 4);
    float* dis     = (float*)alloc((N_NODES + 64) * 4);  // padded: epilogue float4 reads
    float* h       = (float*)alloc((size_t)N_NODES * HID * 4);
    float* hws     = (float*)alloc((size_t)N_NODES * HWS_LD * 4);
    float* agg     = (float*)alloc((size_t)N_NODES * HID * 4);
    float* partial = (float*)alloc((size_t)2 * HID * NSTAT * 4);
    float* AB      = (float*)alloc(2 * HID * 4);
    float* hg      = (float*)alloc((size_t)N_GRAPHS * HID * 4);
    short* Wfrag   = (short*)alloc((size_t)N_LAYERS * 50 * 1024 * 2);

    const int NB_SCAN = (N_NODES + 1023) / 1024;  // 49
    const int NB_GEMM = (N_NODES + BR - 1) / BR;  // 782

    // CSR build (reused across all layers) + W fragment planes
    hipMemsetAsync(hist, 0, N_NODES * 4, stream);
    k_hist<<<(N_EDGES + 255) / 256, 256, 0, stream>>>(ecol, hist);
    k_scan1<<<NB_SCAN, 1024, 0, stream>>>(hist, incl, part);
    k_scan2<<<1, 64, 0, stream>>>(part, NB_SCAN);
    k_scan3<<<NB_SCAN, 1024, 0, stream>>>(incl, hist, part, starts, cursor, dis);
    k_fill<<<(N_EDGES + 255) / 256, 256, 0, stream>>>(erow, ecol, cursor, csr);
    k_wfrag<<<N_LAYERS * 50, 64, 0, stream>>>(Wc, Wfrag);

    for (int l = 0; l < N_LAYERS; l++) {
        const short* wfb = Wfrag + (size_t)l * 50 * 1024;
        if (l == 0)
            k_gemm_fused<0><<<NB_GEMM, 512, 0, stream>>>(wfb, dis, x, emb, agg, AB, h, hws);
        else
            k_gemm_fused<1><<<NB_GEMM, 512, 0, stream>>>(wfb, dis, x, emb, agg, AB, h, hws);
        k_agg<<<(N_NODES + 3) / 4, 256, 0, stream>>>(hws, starts, csr, dis, agg);
        k_bnstat<<<NSTAT, 192, 0, stream>>>(agg, partial);
        k_bncoef<<<(HID + 3) / 4, 256, 0, stream>>>(partial, gamma + l * HID, beta + l * HID, AB);
    }

    k_pool<<<N_GRAPHS, 192, 0, stream>>>(agg, h, AB, batch, hg);
    k_mlp<<<N_GRAPHS, 128, 0, stream>>>(hg, W1, b1, W2, b2, out);
}

// Round 7
// 478.000 us; speedup vs baseline: 2.6230x; 1.1496x over previous
//
#include <hip/hip_runtime.h>

#define N_NODES  50000
#define N_EDGES  500000
#define N_GRAPHS 2000
#define HID      145
#define HID2     72
#define N_LAYERS 4
#define EPS      1e-5f
#define HWS_LD   160   // fp16 row stride for gather target: 320B = 5 aligned 64B lines
#define BR       64    // rows per GEMM block
#define TSB      168   // bf16 tile stride (shorts): 336B rows -> b128 frag reads 2-way (free)
#define NSTAT    1024  // bnstat partial blocks

typedef __attribute__((ext_vector_type(8))) short bf16x8;
typedef __attribute__((ext_vector_type(4))) float f32x4;
typedef __attribute__((ext_vector_type(2))) _Float16 f16x2;

static __device__ __forceinline__ unsigned short f32_to_bf16(float f) {
    unsigned int u = __float_as_uint(f);
    unsigned int r = (u + 0x7FFF + ((u >> 16) & 1)) >> 16;  // RNE; data has no NaN
    return (unsigned short)r;
}
static __device__ __forceinline__ float bf16hi_to_f32(unsigned short h) {
    return __uint_as_float((unsigned int)h << 16);
}

// ---------------- CSR build ----------------

__global__ void k_hist(const int* __restrict__ col, int* __restrict__ hist) {
    int i = blockIdx.x * 256 + threadIdx.x;
    if (i < N_EDGES) atomicAdd(&hist[col[i]], 1);
}

__global__ void k_scan1(const int* __restrict__ cnt, int* __restrict__ incl,
                        int* __restrict__ part) {
    __shared__ int s[1024];
    int i = blockIdx.x * 1024 + threadIdx.x;
    int v = (i < N_NODES) ? cnt[i] : 0;
    s[threadIdx.x] = v;
    __syncthreads();
    for (int d = 1; d < 1024; d <<= 1) {
        int t = (threadIdx.x >= d) ? s[threadIdx.x - d] : 0;
        __syncthreads();
        s[threadIdx.x] += t;
        __syncthreads();
    }
    if (i < N_NODES) incl[i] = s[threadIdx.x];
    if (threadIdx.x == 1023) part[blockIdx.x] = s[1023];
}

__global__ void k_scan2(int* part, int nb) {
    if (threadIdx.x == 0 && blockIdx.x == 0) {
        int acc = 0;
        for (int b = 0; b < nb; b++) { int t = part[b]; part[b] = acc; acc += t; }
    }
}

__global__ void k_scan3(const int* __restrict__ incl, const int* __restrict__ cnt,
                        const int* __restrict__ part, int* __restrict__ starts,
                        int* __restrict__ cursor, float* __restrict__ dis) {
    int i = blockIdx.x * 1024 + threadIdx.x;
    if (i < N_NODES) {
        int st = incl[i] - cnt[i] + part[blockIdx.x];
        starts[i] = st;
        cursor[i] = st;
        dis[i] = rsqrtf((float)(cnt[i] + 1));  // +1 self loop
    }
    if (i == 0) starts[N_NODES] = N_EDGES;
}

__global__ void k_fill(const int* __restrict__ rowv, const int* __restrict__ colv,
                       int* __restrict__ cursor, int* __restrict__ csr) {
    int e = blockIdx.x * 256 + threadIdx.x;
    if (e < N_EDGES) {
        int c = colv[e];
        int p = atomicAdd(&cursor[c], 1);
        csr[p] = rowv[e];
    }
}

// ---------------- W -> fragment-ordered split-bf16 planes (once per call) ----
// Frag fid = layer*50 + kc*10 + ct: 1024 shorts = [hi 512 | lo 512];
// lane l, elem j: B[k = kc*32+(l>>4)*8+j][c = ct*16+(l&15)], zero-padded.

__global__ void k_wfrag(const float* __restrict__ Wc, short* __restrict__ Wfrag) {
    int fid = blockIdx.x;                 // 0..199
    int layer = fid / 50, rem = fid - layer * 50;
    int kc = rem / 10, ct = rem - kc * 10;
    int l = threadIdx.x;                  // 0..63
    const float* Wl = Wc + (size_t)layer * HID * HID;
    short* base = Wfrag + (size_t)fid * 1024 + l * 8;
#pragma unroll
    for (int j = 0; j < 8; j++) {
        int k = kc * 32 + (l >> 4) * 8 + j;
        int c = ct * 16 + (l & 15);
        float v = (k < HID && c < HID) ? Wl[k * HID + c] : 0.f;
        unsigned short hb = f32_to_bf16(v);
        unsigned short lb = f32_to_bf16(v - bf16hi_to_f32(hb));
        base[j] = (short)hb;
        base[512 + j] = (short)lb;
    }
}

// ---------------- fused (BN-apply | embed) + MFMA GEMM ----------------
// Phase 1: v = relu(A*agg+B)+h_old (MODE 1) or emb[x] (MODE 0); write h global
//          and split-bf16 LDS planes (v = hi + lo exactly to ~2^-17).
// Phase 2: 8 waves: rt = w&3 (16-row tile), col-half = (w>>2)*5 (5 x 16-col tiles);
//          K = 5 chunks of 32; D ~= Ah*Bh + Ah*Bl + Al*Bh (3 MFMAs, error ~2^-17).
// Epilogue scales by dis, converts to fp16 -> hws (pad cols are exact zeros).

#define MFMA(a, b, c) __builtin_amdgcn_mfma_f32_16x16x32_bf16(a, b, c, 0, 0, 0)

template <int MODE>
__global__ __launch_bounds__(512, 6) void k_gemm_fused(
    const short* __restrict__ wfb, const float* __restrict__ dis,
    const int* __restrict__ x, const float* __restrict__ emb,
    const float* __restrict__ agg, const float* __restrict__ AB,
    float* __restrict__ h, _Float16* __restrict__ hws) {
    __shared__ short tileH[BR * TSB];
    __shared__ short tileL[BR * TSB];
    __shared__ float sA[HID], sB[HID];
    int t = threadIdx.x;
    int rbase = blockIdx.x * BR;
    if (MODE == 1 && t < HID) { sA[t] = AB[t]; sB[t] = AB[HID + t]; }
    __syncthreads();
    for (int e2 = t; e2 < BR * HID; e2 += 512) {
        int r = e2 / HID;
        int f = e2 - r * HID;
        int gr = rbase + r;
        float v = 0.f;
        if (gr < N_NODES) {
            size_t idx = (size_t)gr * HID + f;
            if (MODE == 0) {
                v = emb[x[gr] * HID + f];
            } else {
                v = fmaf(sA[f], agg[idx], sB[f]);
                v = fmaxf(v, 0.f) + h[idx];
            }
            h[idx] = v;
        }
        unsigned short hb = f32_to_bf16(v);
        unsigned short lb = f32_to_bf16(v - bf16hi_to_f32(hb));
        tileH[r * TSB + f] = (short)hb;
        tileL[r * TSB + f] = (short)lb;
    }
    // zero K-padding cols [145,160)
    for (int idx = t; idx < BR * 15; idx += 512) {
        int r = idx / 15;
        int f = HID + (idx - r * 15);
        tileH[r * TSB + f] = 0;
        tileL[r * TSB + f] = 0;
    }
    __syncthreads();

    int w = t >> 6, l = t & 63;
    int rt = w & 3;
    int c5 = (w >> 2) * 5;                 // col-tile base: 0 or 5
    int arow = rt * 16 + (l & 15);
    int kgrp = (l >> 4) * 8;
    f32x4 acc0 = {}, acc1 = {}, acc2 = {}, acc3 = {}, acc4 = {};
#pragma unroll
    for (int kc = 0; kc < 5; kc++) {
        int ai = arow * TSB + kc * 32 + kgrp;
        bf16x8 ah = *(const bf16x8*)&tileH[ai];
        bf16x8 al = *(const bf16x8*)&tileL[ai];
        const short* p = wfb + (size_t)(kc * 10 + c5) * 1024 + l * 8;
        bf16x8 bh, bl;
#define STEP(ACC, CI)                                                      \
        bh = *(const bf16x8*)(p + (CI) * 1024);                            \
        bl = *(const bf16x8*)(p + (CI) * 1024 + 512);                      \
        ACC = MFMA(ah, bh, ACC);                                           \
        ACC = MFMA(ah, bl, ACC);                                           \
        ACC = MFMA(al, bh, ACC);
        STEP(acc0, 0) STEP(acc1, 1) STEP(acc2, 2) STEP(acc3, 3) STEP(acc4, 4)
#undef STEP
    }
    int rb4 = rbase + rt * 16 + (l >> 4) * 4;
    f32x4 d4 = *(const f32x4*)(dis + rb4);  // dis alloc padded; OOB lanes guarded below
    int colb = c5 * 16 + (l & 15);
#pragma unroll
    for (int r_ = 0; r_ < 4; r_++) {
        int gr = rb4 + r_;
        if (gr < N_NODES) {
            float dd = d4[r_];
            _Float16* row = hws + (size_t)gr * HWS_LD + colb;
            row[0]  = (_Float16)(acc0[r_] * dd);
            row[16] = (_Float16)(acc1[r_] * dd);
            row[32] = (_Float16)(acc2[r_] * dd);
            row[48] = (_Float16)(acc3[r_] * dd);
            row[64] = (_Float16)(acc4[r_] * dd);
        }
    }
}

// ---------------- aggregate: agg[i] = dis[i] * (sum_{src in N(i)} hws[src] + hws[i])
// one wave per node; fp16 rows (320B). Lane l owns half2 idx l (elems 2l,2l+1);
// lanes 0..15 also own half2 idx 64+l (elems 128..159; >=145 is zero pad).
// 8-wide predicated edge loop, f32 accumulation.

__global__ __launch_bounds__(256) void k_agg(const _Float16* __restrict__ hws,
                                             const int* __restrict__ starts,
                                             const int* __restrict__ csr,
                                             const float* __restrict__ dis,
                                             float* __restrict__ agg) {
    int wave = threadIdx.x >> 6;
    int lane = threadIdx.x & 63;
    int i = blockIdx.x * 4 + wave;
    if (i >= N_NODES) return;
    int s = starts[i], e = starts[i + 1];
    bool tl = lane < 16;
    const f16x2* self = (const f16x2*)(hws + (size_t)i * HWS_LD);
    f16x2 sv = self[lane];
    float ax = (float)sv.x, ay = (float)sv.y;
    float bx = 0.f, by = 0.f;
    if (tl) { f16x2 tv = self[64 + lane]; bx = (float)tv.x; by = (float)tv.y; }
    int last = e - 1;
    for (int j = s; j < e; j += 8) {
        int idx[8]; float m[8];
#pragma unroll
        for (int u = 0; u < 8; u++) {
            int jj = j + u;
            bool ok = jj < e;
            idx[u] = csr[ok ? jj : last];
            m[u] = ok ? 1.f : 0.f;
        }
#pragma unroll
        for (int u = 0; u < 8; u++) {
            const f16x2* q = (const f16x2*)(hws + (size_t)idx[u] * HWS_LD);
            f16x2 v = q[lane];
            ax = fmaf((float)v.x, m[u], ax);
            ay = fmaf((float)v.y, m[u], ay);
        }
        if (tl) {
#pragma unroll
            for (int u = 0; u < 8; u++) {
                const f16x2* q = (const f16x2*)(hws + (size_t)idx[u] * HWS_LD);
                f16x2 v = q[64 + lane];
                bx = fmaf((float)v.x, m[u], bx);
                by = fmaf((float)v.y, m[u], by);
            }
        }
    }
    float di = dis[i];
    float* o = agg + (size_t)i * HID;
    int f0 = 2 * lane;
    o[f0] = ax * di;
    o[f0 + 1] = ay * di;
    if (lane < 8) {
        o[128 + 2 * lane] = bx * di;
        o[128 + 2 * lane + 1] = by * di;
    } else if (lane == 8) {
        o[144] = bx * di;
    }
}

// ---------------- BatchNorm stats ----------------
// NSTAT blocks, unroll-4 rows (4 loads in flight/thread). Partials stored
// transposed [2*HID][NSTAT] so the reducer reads coalesced.

__global__ __launch_bounds__(192) void k_bnstat(const float* __restrict__ agg,
                                                float* __restrict__ partial) {
    int t = threadIdx.x;
    if (t >= HID) return;
    int b = blockIdx.x;
    float s = 0.f, q = 0.f;
    for (int r = b; r < N_NODES; r += 4 * NSTAT) {
        int r1 = r + NSTAT, r2 = r + 2 * NSTAT, r3 = r + 3 * NSTAT;
        float v0 = agg[(size_t)r * HID + t];
        float v1 = (r1 < N_NODES) ? agg[(size_t)r1 * HID + t] : 0.f;
        float v2 = (r2 < N_NODES) ? agg[(size_t)r2 * HID + t] : 0.f;
        float v3 = (r3 < N_NODES) ? agg[(size_t)r3 * HID + t] : 0.f;
        s += (v0 + v1) + (v2 + v3);
        q = fmaf(v0, v0, q);
        q = fmaf(v1, v1, q);
        q = fmaf(v2, v2, q);
        q = fmaf(v3, v3, q);
    }
    partial[(size_t)t * NSTAT + b] = s;
    partial[(size_t)(HID + t) * NSTAT + b] = q;
}

// one wave per feature: reduce sum-row & sq-row (coalesced), butterfly, write A/B.

__global__ __launch_bounds__(256) void k_bncoef(const float* __restrict__ partial,
                                                const float* __restrict__ gamma,
                                                const float* __restrict__ beta,
                                                float* __restrict__ AB) {
    int w = blockIdx.x * 4 + (threadIdx.x >> 6);
    int lane = threadIdx.x & 63;
    if (w >= HID) return;
    const float* ps = partial + (size_t)w * NSTAT;
    const float* pq = partial + (size_t)(HID + w) * NSTAT;
    float s = 0.f, q = 0.f;
#pragma unroll
    for (int b = 0; b < NSTAT / 64; b++) {
        s += ps[b * 64 + lane];
        q += pq[b * 64 + lane];
    }
#pragma unroll
    for (int d = 32; d > 0; d >>= 1) {
        s += __shfl_xor(s, d);
        q += __shfl_xor(q, d);
    }
    if (lane == 0) {
        const float inv = 1.f / (float)N_NODES;
        float mu = s * inv;
        float var = q * inv - mu * mu;
        float a = gamma[w] * rsqrtf(var + EPS);
        AB[w] = a;
        AB[HID + w] = beta[w] - mu * a;
    }
}

// ---------------- pool (fused with layer-3 BN apply) + MLP ----------------

__global__ __launch_bounds__(192) void k_pool(const float* __restrict__ agg,
                                              const float* __restrict__ h,
                                              const float* __restrict__ AB,
                                              const int* __restrict__ batch,
                                              float* __restrict__ hg) {
    int g = blockIdx.x;
    int lo = 0, hi = N_NODES;
    while (lo < hi) { int m = (lo + hi) >> 1; if (batch[m] < g) lo = m + 1; else hi = m; }
    int s = lo;
    hi = N_NODES;
    while (lo < hi) { int m = (lo + hi) >> 1; if (batch[m] < g + 1) lo = m + 1; else hi = m; }
    int e = lo;
    int f = threadIdx.x;
    if (f >= HID) return;
    float A = AB[f], B = AB[HID + f];
    float acc = 0.f;
    for (int n = s; n < e; n++) {
        size_t idx = (size_t)n * HID + f;
        float v = fmaf(A, agg[idx], B);
        acc += fmaxf(v, 0.f) + h[idx];
    }
    hg[g * HID + f] = acc / fmaxf((float)(e - s), 1.f);
}

__global__ __launch_bounds__(128) void k_mlp(const float* __restrict__ hg,
                                             const float* __restrict__ W1,
                                             const float* __restrict__ b1,
                                             const float* __restrict__ W2,
                                             const float* __restrict__ b2,
                                             float* __restrict__ out) {
    int g = blockIdx.x;
    int t = threadIdx.x;
    float v = 0.f;
    if (t < HID2) {
        float s = b1[t];
        const float* hgr = hg + g * HID;
        for (int k = 0; k < HID; k++) s = fmaf(hgr[k], W1[k * HID2 + t], s);
        v = fmaxf(s, 0.f) * W2[t];
    }
    __shared__ float red[128];
    red[t] = v;
    __syncthreads();
    for (int d = 64; d > 0; d >>= 1) {
        if (t < d) red[t] += red[t + d];
        __syncthreads();
    }
    if (t == 0) out[g] = red[0] + b2[0];
}

// ---------------- host launch ----------------

extern "C" void kernel_launch(void* const* d_in, const int* in_sizes, int n_in,
                              void* d_out, int out_size, void* d_ws, size_t ws_size,
                              hipStream_t stream) {
    const int*   x     = (const int*)d_in[0];
    const int*   erow  = (const int*)d_in[1];
    const int*   ecol  = erow + N_EDGES;
    const int*   batch = (const int*)d_in[2];
    const float* emb   = (const float*)d_in[3];
    const float* Wc    = (const float*)d_in[4];
    // d_in[5] = bc: unused — BatchNorm cancels a per-feature constant shift
    const float* gamma = (const float*)d_in[6];
    const float* beta  = (const float*)d_in[7];
    const float* W1    = (const float*)d_in[8];
    const float* b1    = (const float*)d_in[9];
    const float* W2    = (const float*)d_in[10];
    const float* b2    = (const float*)d_in[11];
    float* out = (float*)d_out;

    char* wsb = (char*)d_ws;
    size_t off = 0;
    auto alloc = [&](size_t bytes) -> char* {
        char* p = wsb + off;
        off = (off + bytes + 255) & ~(size_t)255;
        return p;
    };
    int*      hist    = (int*)alloc(N_NODES * 4);
    int*      incl    = (int*)alloc(N_NODES * 4);
    int*      part    = (int*)alloc(64 * 4);
    int*      starts  = (int*)alloc((N_NODES + 1) * 4);
    int*      cursor  = (int*)alloc(N_NODES * 4);
    int*      csr     = (int*)alloc(N_EDGES * 4);
    float*    dis     = (float*)alloc((N_NODES + 64) * 4);  // padded: epilogue float4 reads
    float*    h       = (float*)alloc((size_t)N_NODES * HID * 4);
    _Float16* hws     = (_Float16*)alloc((size_t)N_NODES * HWS_LD * 2);
    float*    agg     = (float*)alloc((size_t)N_NODES * HID * 4);
    float*    partial = (float*)alloc((size_t)2 * HID * NSTAT * 4);
    float*    AB      = (float*)alloc(2 * HID * 4);
    float*    hg      = (float*)alloc((size_t)N_GRAPHS * HID * 4);
    short*    Wfrag   = (short*)alloc((size_t)N_LAYERS * 50 * 1024 * 2);

    const int NB_SCAN = (N_NODES + 1023) / 1024;  // 49
    const int NB_GEMM = (N_NODES + BR - 1) / BR;  // 782

    // CSR build (reused across all layers) + W fragment planes
    hipMemsetAsync(hist, 0, N_NODES * 4, stream);
    k_hist<<<(N_EDGES + 255) / 256, 256, 0, stream>>>(ecol, hist);
    k_scan1<<<NB_SCAN, 1024, 0, stream>>>(hist, incl, part);
    k_scan2<<<1, 64, 0, stream>>>(part, NB_SCAN);
    k_scan3<<<NB_SCAN, 1024, 0, stream>>>(incl, hist, part, starts, cursor, dis);
    k_fill<<<(N_EDGES + 255) / 256, 256, 0, stream>>>(erow, ecol, cursor, csr);
    k_wfrag<<<N_LAYERS * 50, 64, 0, stream>>>(Wc, Wfrag);

    for (int l = 0; l < N_LAYERS; l++) {
        const short* wfb = Wfrag + (size_t)l * 50 * 1024;
        if (l == 0)
            k_gemm_fused<0><<<NB_GEMM, 512, 0, stream>>>(wfb, dis, x, emb, agg, AB, h, hws);
        else
            k_gemm_fused<1><<<NB_GEMM, 512, 0, stream>>>(wfb, dis, x, emb, agg, AB, h, hws);
        k_agg<<<(N_NODES + 3) / 4, 256, 0, stream>>>(hws, starts, csr, dis, agg);
        k_bnstat<<<NSTAT, 192, 0, stream>>>(agg, partial);
        k_bncoef<<<(HID + 3) / 4, 256, 0, stream>>>(partial, gamma + l * HID, beta + l * HID, AB);
    }

    k_pool<<<N_GRAPHS, 192, 0, stream>>>(agg, h, AB, batch, hg);
    k_mlp<<<N_GRAPHS, 128, 0, stream>>>(hg, W1, b1, W2, b2, out);
}

// Round 8
// 441.768 us; speedup vs baseline: 2.8381x; 1.0820x over previous
//
#include <hip/hip_runtime.h>

#define N_NODES  50000
#define N_EDGES  500000
#define N_GRAPHS 2000
#define HID      145
#define HID2     72
#define N_LAYERS 4
#define EPS      1e-5f
#define HWS_LD   160   // fp16 gather row stride: 320B = 5 aligned 64B lines
#define AGG_LD   146   // fp16 agg/h row stride: 292B, 4B-aligned rows for half2
#define BR       64    // rows per GEMM block
#define TSB      168   // bf16 tile stride (shorts): 336B rows -> b128 frag reads 2-way (free)
#define NBKT     64    // BN-stat atomic buckets

typedef __attribute__((ext_vector_type(8))) short bf16x8;
typedef __attribute__((ext_vector_type(4))) float f32x4;
typedef __attribute__((ext_vector_type(2))) _Float16 f16x2;

static __device__ __forceinline__ unsigned short f32_to_bf16(float f) {
    unsigned int u = __float_as_uint(f);
    unsigned int r = (u + 0x7FFF + ((u >> 16) & 1)) >> 16;  // RNE; data has no NaN
    return (unsigned short)r;
}
static __device__ __forceinline__ float bf16hi_to_f32(unsigned short h) {
    return __uint_as_float((unsigned int)h << 16);
}

// ---------------- CSR build ----------------

__global__ void k_hist(const int* __restrict__ col, int* __restrict__ hist) {
    int i = blockIdx.x * 256 + threadIdx.x;
    if (i < N_EDGES) atomicAdd(&hist[col[i]], 1);
}

__global__ void k_scan1(const int* __restrict__ cnt, int* __restrict__ incl,
                        int* __restrict__ part) {
    __shared__ int s[1024];
    int i = blockIdx.x * 1024 + threadIdx.x;
    int v = (i < N_NODES) ? cnt[i] : 0;
    s[threadIdx.x] = v;
    __syncthreads();
    for (int d = 1; d < 1024; d <<= 1) {
        int t = (threadIdx.x >= d) ? s[threadIdx.x - d] : 0;
        __syncthreads();
        s[threadIdx.x] += t;
        __syncthreads();
    }
    if (i < N_NODES) incl[i] = s[threadIdx.x];
    if (threadIdx.x == 1023) part[blockIdx.x] = s[1023];
}

__global__ void k_scan2(int* part, int nb) {
    if (threadIdx.x == 0 && blockIdx.x == 0) {
        int acc = 0;
        for (int b = 0; b < nb; b++) { int t = part[b]; part[b] = acc; acc += t; }
    }
}

__global__ void k_scan3(const int* __restrict__ incl, const int* __restrict__ cnt,
                        const int* __restrict__ part, int* __restrict__ starts,
                        int* __restrict__ cursor, float* __restrict__ dis) {
    int i = blockIdx.x * 1024 + threadIdx.x;
    if (i < N_NODES) {
        int st = incl[i] - cnt[i] + part[blockIdx.x];
        starts[i] = st;
        cursor[i] = st;
        dis[i] = rsqrtf((float)(cnt[i] + 1));  // +1 self loop
    }
    if (i == 0) starts[N_NODES] = N_EDGES;
}

__global__ void k_fill(const int* __restrict__ rowv, const int* __restrict__ colv,
                       int* __restrict__ cursor, int* __restrict__ csr) {
    int e = blockIdx.x * 256 + threadIdx.x;
    if (e < N_EDGES) {
        int c = colv[e];
        int p = atomicAdd(&cursor[c], 1);
        csr[p] = rowv[e];
    }
}

// ---------------- W -> fragment-ordered split-bf16 planes (once per call) ----
// Frag fid = layer*50 + kc*10 + ct: 1024 shorts = [hi 512 | lo 512];
// lane l, elem j: B[k = kc*32+(l>>4)*8+j][c = ct*16+(l&15)], zero-padded.

__global__ void k_wfrag(const float* __restrict__ Wc, short* __restrict__ Wfrag) {
    int fid = blockIdx.x;                 // 0..199
    int layer = fid / 50, rem = fid - layer * 50;
    int kc = rem / 10, ct = rem - kc * 10;
    int l = threadIdx.x;                  // 0..63
    const float* Wl = Wc + (size_t)layer * HID * HID;
    short* base = Wfrag + (size_t)fid * 1024 + l * 8;
#pragma unroll
    for (int j = 0; j < 8; j++) {
        int k = kc * 32 + (l >> 4) * 8 + j;
        int c = ct * 16 + (l & 15);
        float v = (k < HID && c < HID) ? Wl[k * HID + c] : 0.f;
        unsigned short hb = f32_to_bf16(v);
        unsigned short lb = f32_to_bf16(v - bf16hi_to_f32(hb));
        base[j] = (short)hb;
        base[512 + j] = (short)lb;
    }
}

// ---------------- fused (BN-apply | embed) + MFMA GEMM ----------------
// Phase 1: v = relu(A*agg+B)+h_old (MODE 1) or emb[x] (MODE 0); h stored fp16,
//          split-bf16 LDS planes (v_fp16 = hi + lo exactly to ~2^-17).
// Phase 2: 8 waves: rt = w&3 (16-row tile), col-half = (w>>2)*5 (5 x 16-col tiles);
//          K = 5 chunks of 32; D ~= Ah*Bh + Ah*Bl + Al*Bh (3 MFMAs).
// Epilogue scales by dis, converts to fp16 -> hws (pad cols are exact zeros).

#define MFMA(a, b, c) __builtin_amdgcn_mfma_f32_16x16x32_bf16(a, b, c, 0, 0, 0)

template <int MODE>
__global__ __launch_bounds__(512, 6) void k_gemm_fused(
    const short* __restrict__ wfb, const float* __restrict__ dis,
    const int* __restrict__ x, const float* __restrict__ emb,
    const _Float16* __restrict__ agg, const float* __restrict__ AB,
    _Float16* __restrict__ h, _Float16* __restrict__ hws) {
    __shared__ short tileH[BR * TSB];
    __shared__ short tileL[BR * TSB];
    __shared__ float sA[HID], sB[HID];
    int t = threadIdx.x;
    int rbase = blockIdx.x * BR;
    if (MODE == 1 && t < HID) { sA[t] = AB[t]; sB[t] = AB[HID + t]; }
    __syncthreads();
    for (int e2 = t; e2 < BR * HID; e2 += 512) {
        int r = e2 / HID;
        int f = e2 - r * HID;
        int gr = rbase + r;
        float v = 0.f;
        if (gr < N_NODES) {
            size_t idx = (size_t)gr * AGG_LD + f;
            if (MODE == 0) {
                v = emb[x[gr] * HID + f];
            } else {
                v = fmaf(sA[f], (float)agg[idx], sB[f]);
                v = fmaxf(v, 0.f) + (float)h[idx];
            }
            h[idx] = (_Float16)v;
        }
        unsigned short hb = f32_to_bf16(v);
        unsigned short lb = f32_to_bf16(v - bf16hi_to_f32(hb));
        tileH[r * TSB + f] = (short)hb;
        tileL[r * TSB + f] = (short)lb;
    }
    // zero K-padding cols [145,160)
    for (int idx = t; idx < BR * 15; idx += 512) {
        int r = idx / 15;
        int f = HID + (idx - r * 15);
        tileH[r * TSB + f] = 0;
        tileL[r * TSB + f] = 0;
    }
    __syncthreads();

    int w = t >> 6, l = t & 63;
    int rt = w & 3;
    int c5 = (w >> 2) * 5;                 // col-tile base: 0 or 5
    int arow = rt * 16 + (l & 15);
    int kgrp = (l >> 4) * 8;
    f32x4 acc0 = {}, acc1 = {}, acc2 = {}, acc3 = {}, acc4 = {};
#pragma unroll
    for (int kc = 0; kc < 5; kc++) {
        int ai = arow * TSB + kc * 32 + kgrp;
        bf16x8 ah = *(const bf16x8*)&tileH[ai];
        bf16x8 al = *(const bf16x8*)&tileL[ai];
        const short* p = wfb + (size_t)(kc * 10 + c5) * 1024 + l * 8;
        bf16x8 bh, bl;
#define STEP(ACC, CI)                                                      \
        bh = *(const bf16x8*)(p + (CI) * 1024);                            \
        bl = *(const bf16x8*)(p + (CI) * 1024 + 512);                      \
        ACC = MFMA(ah, bh, ACC);                                           \
        ACC = MFMA(ah, bl, ACC);                                           \
        ACC = MFMA(al, bh, ACC);
        STEP(acc0, 0) STEP(acc1, 1) STEP(acc2, 2) STEP(acc3, 3) STEP(acc4, 4)
#undef STEP
    }
    int rb4 = rbase + rt * 16 + (l >> 4) * 4;
    f32x4 d4 = *(const f32x4*)(dis + rb4);  // dis alloc padded; OOB lanes guarded below
    int colb = c5 * 16 + (l & 15);
#pragma unroll
    for (int r_ = 0; r_ < 4; r_++) {
        int gr = rb4 + r_;
        if (gr < N_NODES) {
            float dd = d4[r_];
            _Float16* row = hws + (size_t)gr * HWS_LD + colb;
            row[0]  = (_Float16)(acc0[r_] * dd);
            row[16] = (_Float16)(acc1[r_] * dd);
            row[32] = (_Float16)(acc2[r_] * dd);
            row[48] = (_Float16)(acc3[r_] * dd);
            row[64] = (_Float16)(acc4[r_] * dd);
        }
    }
}

// ---------------- aggregate + fused BN partial stats ----------------
// agg[i] = dis[i] * (sum_{src in N(i)} hws[src] + hws[i]); one wave per node
// (grid exact: 12500 blocks x 4 waves = 50000). 8-wide predicated edge loop.
// BN stats: per-block LDS reduce (direct-indexed) -> 64-bucket global atomics.

__global__ __launch_bounds__(256) void k_agg(const _Float16* __restrict__ hws,
                                             const int* __restrict__ starts,
                                             const int* __restrict__ csr,
                                             const float* __restrict__ dis,
                                             _Float16* __restrict__ agg,
                                             float* __restrict__ gpart) {
    __shared__ float sS[4][AGG_LD], sQ[4][AGG_LD];
    int t = threadIdx.x;
    int wave = t >> 6;
    int lane = t & 63;
    int i = blockIdx.x * 4 + wave;   // always < N_NODES (exact grid)
    int s = starts[i], e = starts[i + 1];
    bool tl = lane < 9;
    const f16x2* self = (const f16x2*)(hws + (size_t)i * HWS_LD);
    f16x2 sv = self[lane];
    float ax = (float)sv.x, ay = (float)sv.y;
    float bx = 0.f, by = 0.f;
    if (tl) { f16x2 tv = self[64 + lane]; bx = (float)tv.x; by = (float)tv.y; }
    int last = e - 1;
    for (int j = s; j < e; j += 8) {
        int idx[8]; float m[8];
#pragma unroll
        for (int u = 0; u < 8; u++) {
            int jj = j + u;
            bool ok = jj < e;
            idx[u] = csr[ok ? jj : last];
            m[u] = ok ? 1.f : 0.f;
        }
#pragma unroll
        for (int u = 0; u < 8; u++) {
            const f16x2* q = (const f16x2*)(hws + (size_t)idx[u] * HWS_LD);
            f16x2 v = q[lane];
            ax = fmaf((float)v.x, m[u], ax);
            ay = fmaf((float)v.y, m[u], ay);
        }
        if (tl) {
#pragma unroll
            for (int u = 0; u < 8; u++) {
                const f16x2* q = (const f16x2*)(hws + (size_t)idx[u] * HWS_LD);
                f16x2 v = q[64 + lane];
                bx = fmaf((float)v.x, m[u], bx);
                by = fmaf((float)v.y, m[u], by);
            }
        }
    }
    float di = dis[i];
    float v0 = ax * di, v1 = ay * di;          // features 2l, 2l+1
    float v2 = bx * di;                        // feature 128+2l (lane<9)
    float v3 = (lane < 8) ? by * di : 0.f;     // feature 129+2l; lane8 slot 145 = pad

    f16x2* o2 = (f16x2*)(agg + (size_t)i * AGG_LD);
    o2[lane] = f16x2{(_Float16)v0, (_Float16)v1};
    if (tl) o2[64 + lane] = f16x2{(_Float16)v2, (_Float16)v3};

    // per-block BN partials (direct-indexed LDS; every slot written exactly once)
    sS[wave][2 * lane] = v0;     sQ[wave][2 * lane] = v0 * v0;
    sS[wave][2 * lane + 1] = v1; sQ[wave][2 * lane + 1] = v1 * v1;
    if (tl) {
        sS[wave][128 + 2 * lane] = v2; sQ[wave][128 + 2 * lane] = v2 * v2;
        sS[wave][129 + 2 * lane] = v3; sQ[wave][129 + 2 * lane] = v3 * v3;
    }
    __syncthreads();
    int bucket = blockIdx.x & (NBKT - 1);
    float* gp = gpart + (size_t)bucket * (2 * AGG_LD);
    for (int idx2 = t; idx2 < 2 * AGG_LD; idx2 += 256) {
        float v = (idx2 < AGG_LD)
                      ? ((sS[0][idx2] + sS[1][idx2]) + (sS[2][idx2] + sS[3][idx2]))
                      : ((sQ[0][idx2 - AGG_LD] + sQ[1][idx2 - AGG_LD]) +
                         (sQ[2][idx2 - AGG_LD] + sQ[3][idx2 - AGG_LD]));
        atomicAdd(&gp[idx2], v);
    }
}

// ---------------- BN coefficients: one wave per feature, reduce 64 buckets,
// then zero the buckets for the next layer's atomics. ----------------

__global__ __launch_bounds__(256) void k_bncoef(float* __restrict__ gpart,
                                                const float* __restrict__ gamma,
                                                const float* __restrict__ beta,
                                                float* __restrict__ AB) {
    int w = blockIdx.x * 4 + (threadIdx.x >> 6);
    int lane = threadIdx.x & 63;
    if (w >= HID) return;
    float* ps = gpart + (size_t)lane * (2 * AGG_LD) + w;
    float s = ps[0];
    float q = ps[AGG_LD];
#pragma unroll
    for (int d = 32; d > 0; d >>= 1) {
        s += __shfl_xor(s, d);
        q += __shfl_xor(q, d);
    }
    ps[0] = 0.f;        // re-zero buckets for next layer
    ps[AGG_LD] = 0.f;
    if (lane == 0) {
        const float inv = 1.f / (float)N_NODES;
        float mu = s * inv;
        float var = q * inv - mu * mu;
        float a = gamma[w] * rsqrtf(var + EPS);
        AB[w] = a;
        AB[HID + w] = beta[w] - mu * a;
    }
}

// ---------------- pool (fused layer-3 BN apply) + MLP, one block per graph ----

__global__ __launch_bounds__(192) void k_pool_mlp(
    const _Float16* __restrict__ agg, const _Float16* __restrict__ h,
    const float* __restrict__ AB, const int* __restrict__ batch,
    const float* __restrict__ W1, const float* __restrict__ b1,
    const float* __restrict__ W2, const float* __restrict__ b2,
    float* __restrict__ out) {
    __shared__ float sH[HID];
    __shared__ float red[128];
    int g = blockIdx.x;
    int lo = 0, hi = N_NODES;
    while (lo < hi) { int m = (lo + hi) >> 1; if (batch[m] < g) lo = m + 1; else hi = m; }
    int s = lo;
    hi = N_NODES;
    while (lo < hi) { int m = (lo + hi) >> 1; if (batch[m] < g + 1) lo = m + 1; else hi = m; }
    int e = lo;
    int f = threadIdx.x;
    if (f < HID) {
        float A = AB[f], B = AB[HID + f];
        float acc = 0.f;
        for (int n = s; n < e; n++) {
            size_t idx = (size_t)n * AGG_LD + f;
            float v = fmaf(A, (float)agg[idx], B);
            acc += fmaxf(v, 0.f) + (float)h[idx];
        }
        sH[f] = acc / fmaxf((float)(e - s), 1.f);
    }
    __syncthreads();
    int t = threadIdx.x;
    float v = 0.f;
    if (t < HID2) {
        float acc = b1[t];
        for (int k = 0; k < HID; k++) acc = fmaf(sH[k], W1[k * HID2 + t], acc);
        v = fmaxf(acc, 0.f) * W2[t];
    }
    if (t < 128) red[t] = v;
    __syncthreads();
    for (int d = 64; d > 0; d >>= 1) {
        if (t < d) red[t] += red[t + d];
        __syncthreads();
    }
    if (t == 0) out[g] = red[0] + b2[0];
}

// ---------------- host launch ----------------

extern "C" void kernel_launch(void* const* d_in, const int* in_sizes, int n_in,
                              void* d_out, int out_size, void* d_ws, size_t ws_size,
                              hipStream_t stream) {
    const int*   x     = (const int*)d_in[0];
    const int*   erow  = (const int*)d_in[1];
    const int*   ecol  = erow + N_EDGES;
    const int*   batch = (const int*)d_in[2];
    const float* emb   = (const float*)d_in[3];
    const float* Wc    = (const float*)d_in[4];
    // d_in[5] = bc: unused — BatchNorm cancels a per-feature constant shift
    const float* gamma = (const float*)d_in[6];
    const float* beta  = (const float*)d_in[7];
    const float* W1    = (const float*)d_in[8];
    const float* b1    = (const float*)d_in[9];
    const float* W2    = (const float*)d_in[10];
    const float* b2    = (const float*)d_in[11];
    float* out = (float*)d_out;

    char* wsb = (char*)d_ws;
    size_t off = 0;
    auto alloc = [&](size_t bytes) -> char* {
        char* p = wsb + off;
        off = (off + bytes + 255) & ~(size_t)255;
        return p;
    };
    int*      hist    = (int*)alloc(N_NODES * 4);
    int*      incl    = (int*)alloc(N_NODES * 4);
    int*      part    = (int*)alloc(64 * 4);
    int*      starts  = (int*)alloc((N_NODES + 1) * 4);
    int*      cursor  = (int*)alloc(N_NODES * 4);
    int*      csr     = (int*)alloc(N_EDGES * 4);
    float*    dis     = (float*)alloc((N_NODES + 64) * 4);  // padded: epilogue float4 reads
    _Float16* h       = (_Float16*)alloc((size_t)N_NODES * AGG_LD * 2);
    _Float16* hws     = (_Float16*)alloc((size_t)N_NODES * HWS_LD * 2);
    _Float16* agg     = (_Float16*)alloc((size_t)N_NODES * AGG_LD * 2);
    float*    gpart   = (float*)alloc((size_t)NBKT * 2 * AGG_LD * 4);
    float*    AB      = (float*)alloc(2 * HID * 4);
    short*    Wfrag   = (short*)alloc((size_t)N_LAYERS * 50 * 1024 * 2);

    const int NB_SCAN = (N_NODES + 1023) / 1024;  // 49
    const int NB_GEMM = (N_NODES + BR - 1) / BR;  // 782

    // CSR build (reused across all layers) + W fragment planes + stat buckets
    hipMemsetAsync(hist, 0, N_NODES * 4, stream);
    hipMemsetAsync(gpart, 0, (size_t)NBKT * 2 * AGG_LD * 4, stream);
    k_hist<<<(N_EDGES + 255) / 256, 256, 0, stream>>>(ecol, hist);
    k_scan1<<<NB_SCAN, 1024, 0, stream>>>(hist, incl, part);
    k_scan2<<<1, 64, 0, stream>>>(part, NB_SCAN);
    k_scan3<<<NB_SCAN, 1024, 0, stream>>>(incl, hist, part, starts, cursor, dis);
    k_fill<<<(N_EDGES + 255) / 256, 256, 0, stream>>>(erow, ecol, cursor, csr);
    k_wfrag<<<N_LAYERS * 50, 64, 0, stream>>>(Wc, Wfrag);

    for (int l = 0; l < N_LAYERS; l++) {
        const short* wfb = Wfrag + (size_t)l * 50 * 1024;
        if (l == 0)
            k_gemm_fused<0><<<NB_GEMM, 512, 0, stream>>>(wfb, dis, x, emb, agg, AB, h, hws);
        else
            k_gemm_fused<1><<<NB_GEMM, 512, 0, stream>>>(wfb, dis, x, emb, agg, AB, h, hws);
        k_agg<<<N_NODES / 4, 256, 0, stream>>>(hws, starts, csr, dis, agg, gpart);
        k_bncoef<<<(HID + 3) / 4, 256, 0, stream>>>(gpart, gamma + l * HID, beta + l * HID, AB);
    }

    k_pool_mlp<<<N_GRAPHS, 192, 0, stream>>>(agg, h, AB, batch, W1, b1, W2, b2, out);
}

// Round 9
// 419.848 us; speedup vs baseline: 2.9863x; 1.0522x over previous
//
#include <hip/hip_runtime.h>

#define N_NODES  50000
#define N_EDGES  500000
#define N_GRAPHS 2000
#define HID      145
#define HID2     72
#define N_LAYERS 4
#define EPS      1e-5f
#define HWS_LD   160   // fp16 gather row stride: 320B = 5 aligned 64B lines
#define AGG_LD   152   // fp16 agg/h row stride: 304B, 16B-aligned rows (f16x8 chunks)
#define BR       64    // rows per GEMM block
#define TSB      168   // bf16 tile stride (shorts): 336B rows -> b128 frag reads 2-way (free)
#define NBKT     64    // BN-stat atomic buckets

typedef __attribute__((ext_vector_type(8))) short bf16x8;
typedef __attribute__((ext_vector_type(4))) float f32x4;
typedef __attribute__((ext_vector_type(2))) _Float16 f16x2;
typedef __attribute__((ext_vector_type(8))) _Float16 f16x8;

static __device__ __forceinline__ unsigned short f32_to_bf16(float f) {
    unsigned int u = __float_as_uint(f);
    unsigned int r = (u + 0x7FFF + ((u >> 16) & 1)) >> 16;  // RNE; data has no NaN
    return (unsigned short)r;
}
static __device__ __forceinline__ float bf16hi_to_f32(unsigned short h) {
    return __uint_as_float((unsigned int)h << 16);
}

// ---------------- CSR build ----------------

__global__ void k_hist(const int* __restrict__ col, int* __restrict__ hist) {
    int i = blockIdx.x * 256 + threadIdx.x;
    if (i < N_EDGES) atomicAdd(&hist[col[i]], 1);
}

__global__ void k_scan1(const int* __restrict__ cnt, int* __restrict__ incl,
                        int* __restrict__ part) {
    __shared__ int s[1024];
    int i = blockIdx.x * 1024 + threadIdx.x;
    int v = (i < N_NODES) ? cnt[i] : 0;
    s[threadIdx.x] = v;
    __syncthreads();
    for (int d = 1; d < 1024; d <<= 1) {
        int t = (threadIdx.x >= d) ? s[threadIdx.x - d] : 0;
        __syncthreads();
        s[threadIdx.x] += t;
        __syncthreads();
    }
    if (i < N_NODES) incl[i] = s[threadIdx.x];
    if (threadIdx.x == 1023) part[blockIdx.x] = s[1023];
}

__global__ void k_scan2(int* part, int nb) {
    if (threadIdx.x == 0 && blockIdx.x == 0) {
        int acc = 0;
        for (int b = 0; b < nb; b++) { int t = part[b]; part[b] = acc; acc += t; }
    }
}

__global__ void k_scan3(const int* __restrict__ incl, const int* __restrict__ cnt,
                        const int* __restrict__ part, int* __restrict__ starts,
                        int* __restrict__ cursor, float* __restrict__ dis) {
    int i = blockIdx.x * 1024 + threadIdx.x;
    if (i < N_NODES) {
        int st = incl[i] - cnt[i] + part[blockIdx.x];
        starts[i] = st;
        cursor[i] = st;
        dis[i] = rsqrtf((float)(cnt[i] + 1));  // +1 self loop
    }
    if (i == 0) starts[N_NODES] = N_EDGES;
}

__global__ void k_fill(const int* __restrict__ rowv, const int* __restrict__ colv,
                       int* __restrict__ cursor, int* __restrict__ csr) {
    int e = blockIdx.x * 256 + threadIdx.x;
    if (e < N_EDGES) {
        int c = colv[e];
        int p = atomicAdd(&cursor[c], 1);
        csr[p] = rowv[e];
    }
}

// ---------------- W -> fragment-ordered split-bf16 planes (once per call) ----
// Frag fid = layer*50 + kc*10 + ct: 1024 shorts = [hi 512 | lo 512];
// lane l, elem j: B[k = kc*32+(l>>4)*8+j][c = ct*16+(l&15)], zero-padded.

__global__ void k_wfrag(const float* __restrict__ Wc, short* __restrict__ Wfrag) {
    int fid = blockIdx.x;                 // 0..199
    int layer = fid / 50, rem = fid - layer * 50;
    int kc = rem / 10, ct = rem - kc * 10;
    int l = threadIdx.x;                  // 0..63
    const float* Wl = Wc + (size_t)layer * HID * HID;
    short* base = Wfrag + (size_t)fid * 1024 + l * 8;
#pragma unroll
    for (int j = 0; j < 8; j++) {
        int k = kc * 32 + (l >> 4) * 8 + j;
        int c = ct * 16 + (l & 15);
        float v = (k < HID && c < HID) ? Wl[k * HID + c] : 0.f;
        unsigned short hb = f32_to_bf16(v);
        unsigned short lb = f32_to_bf16(v - bf16hi_to_f32(hb));
        base[j] = (short)hb;
        base[512 + j] = (short)lb;
    }
}

// ---------------- fused (BN-apply | embed) + MFMA GEMM ----------------
// Phase 1 (vectorized f16x8): v = relu(A*agg+B)+h_old (MODE 1) or emb[x]
//          (MODE 0); h stored fp16; split-bf16 LDS planes. Rows processed as
//          19 x f16x8 chunks (AGG_LD=152, 16B-aligned); pad features 145..151
//          predicated to exact zero; K-pad 152..159 zeroed separately.
// Phase 2: 8 waves: rt = w&3 (16-row tile), col-half = (w>>2)*5 (5 x 16-col
//          tiles); K = 5 chunks of 32; D ~= Ah*Bh + Ah*Bl + Al*Bh.
// Epilogue scales by dis, converts to fp16 -> hws (pad cols are exact zeros).

#define MFMA(a, b, c) __builtin_amdgcn_mfma_f32_16x16x32_bf16(a, b, c, 0, 0, 0)

template <int MODE>
__global__ __launch_bounds__(512, 6) void k_gemm_fused(
    const short* __restrict__ wfb, const float* __restrict__ dis,
    const int* __restrict__ x, const float* __restrict__ emb,
    const _Float16* __restrict__ agg, const float* __restrict__ AB,
    _Float16* __restrict__ h, _Float16* __restrict__ hws) {
    __shared__ short tileH[BR * TSB];
    __shared__ short tileL[BR * TSB];
    __shared__ float sA[HID], sB[HID];
    int t = threadIdx.x;
    int rbase = blockIdx.x * BR;
    if (MODE == 1 && t < HID) { sA[t] = AB[t]; sB[t] = AB[HID + t]; }
    __syncthreads();
    for (int idx = t; idx < BR * 19; idx += 512) {
        int r = idx / 19;
        int c = idx - r * 19;
        int f0 = c * 8;
        int gr = rbase + r;
        float vv[8];
        if (gr < N_NODES) {
            size_t base = (size_t)gr * AGG_LD + f0;
            if (MODE == 0) {
                const float* er = emb + x[gr] * HID;
#pragma unroll
                for (int j = 0; j < 8; j++) {
                    int f = f0 + j;
                    vv[j] = (f < HID) ? er[f] : 0.f;
                }
            } else {
                f16x8 av = *(const f16x8*)(agg + base);
                f16x8 hv = *(const f16x8*)(h + base);
#pragma unroll
                for (int j = 0; j < 8; j++) {
                    int f = f0 + j;
                    float vj = 0.f;
                    if (f < HID) {
                        vj = fmaf(sA[f], (float)av[j], sB[f]);
                        vj = fmaxf(vj, 0.f) + (float)hv[j];
                    }
                    vv[j] = vj;
                }
            }
            f16x8 hst;
#pragma unroll
            for (int j = 0; j < 8; j++) hst[j] = (_Float16)vv[j];
            *(f16x8*)(h + base) = hst;
        } else {
#pragma unroll
            for (int j = 0; j < 8; j++) vv[j] = 0.f;
        }
        bf16x8 bh, bl;
#pragma unroll
        for (int j = 0; j < 8; j++) {
            unsigned short hb = f32_to_bf16(vv[j]);
            bh[j] = (short)hb;
            bl[j] = (short)f32_to_bf16(vv[j] - bf16hi_to_f32(hb));
        }
        *(bf16x8*)&tileH[r * TSB + f0] = bh;
        *(bf16x8*)&tileL[r * TSB + f0] = bl;
    }
    // zero K-padding cols [152,160)
    if (t < BR) {
        bf16x8 z = {};
        *(bf16x8*)&tileH[t * TSB + 152] = z;
        *(bf16x8*)&tileL[t * TSB + 152] = z;
    }
    __syncthreads();

    int w = t >> 6, l = t & 63;
    int rt = w & 3;
    int c5 = (w >> 2) * 5;                 // col-tile base: 0 or 5
    int arow = rt * 16 + (l & 15);
    int kgrp = (l >> 4) * 8;
    f32x4 acc0 = {}, acc1 = {}, acc2 = {}, acc3 = {}, acc4 = {};
#pragma unroll
    for (int kc = 0; kc < 5; kc++) {
        int ai = arow * TSB + kc * 32 + kgrp;
        bf16x8 ah = *(const bf16x8*)&tileH[ai];
        bf16x8 al = *(const bf16x8*)&tileL[ai];
        const short* p = wfb + (size_t)(kc * 10 + c5) * 1024 + l * 8;
        bf16x8 bh, bl;
#define STEP(ACC, CI)                                                      \
        bh = *(const bf16x8*)(p + (CI) * 1024);                            \
        bl = *(const bf16x8*)(p + (CI) * 1024 + 512);                      \
        ACC = MFMA(ah, bh, ACC);                                           \
        ACC = MFMA(ah, bl, ACC);                                           \
        ACC = MFMA(al, bh, ACC);
        STEP(acc0, 0) STEP(acc1, 1) STEP(acc2, 2) STEP(acc3, 3) STEP(acc4, 4)
#undef STEP
    }
    int rb4 = rbase + rt * 16 + (l >> 4) * 4;
    f32x4 d4 = *(const f32x4*)(dis + rb4);  // dis alloc padded; OOB lanes guarded below
    int colb = c5 * 16 + (l & 15);
#pragma unroll
    for (int r_ = 0; r_ < 4; r_++) {
        int gr = rb4 + r_;
        if (gr < N_NODES) {
            float dd = d4[r_];
            _Float16* row = hws + (size_t)gr * HWS_LD + colb;
            row[0]  = (_Float16)(acc0[r_] * dd);
            row[16] = (_Float16)(acc1[r_] * dd);
            row[32] = (_Float16)(acc2[r_] * dd);
            row[48] = (_Float16)(acc3[r_] * dd);
            row[64] = (_Float16)(acc4[r_] * dd);
        }
    }
}

// ---------------- aggregate + fused BN partial stats ----------------
// agg[i] = dis[i] * (sum_{src in N(i)} hws[src] + hws[i]); one wave per node
// (grid exact: 12500 blocks x 4 waves = 50000). 8-wide predicated edge loop.
// BN stats: per-block LDS reduce (direct-indexed) -> 64-bucket global atomics.

__global__ __launch_bounds__(256) void k_agg(const _Float16* __restrict__ hws,
                                             const int* __restrict__ starts,
                                             const int* __restrict__ csr,
                                             const float* __restrict__ dis,
                                             _Float16* __restrict__ agg,
                                             float* __restrict__ gpart) {
    __shared__ float sS[4][AGG_LD], sQ[4][AGG_LD];
    int t = threadIdx.x;
    int wave = t >> 6;
    int lane = t & 63;
    int i = blockIdx.x * 4 + wave;   // always < N_NODES (exact grid)
    int s = starts[i], e = starts[i + 1];
    bool tl = lane < 9;
    const f16x2* self = (const f16x2*)(hws + (size_t)i * HWS_LD);
    f16x2 sv = self[lane];
    float ax = (float)sv.x, ay = (float)sv.y;
    float bx = 0.f, by = 0.f;
    if (tl) { f16x2 tv = self[64 + lane]; bx = (float)tv.x; by = (float)tv.y; }
    int last = e - 1;
    for (int j = s; j < e; j += 8) {
        int idx[8]; float m[8];
#pragma unroll
        for (int u = 0; u < 8; u++) {
            int jj = j + u;
            bool ok = jj < e;
            idx[u] = csr[ok ? jj : last];
            m[u] = ok ? 1.f : 0.f;
        }
#pragma unroll
        for (int u = 0; u < 8; u++) {
            const f16x2* q = (const f16x2*)(hws + (size_t)idx[u] * HWS_LD);
            f16x2 v = q[lane];
            ax = fmaf((float)v.x, m[u], ax);
            ay = fmaf((float)v.y, m[u], ay);
        }
        if (tl) {
#pragma unroll
            for (int u = 0; u < 8; u++) {
                const f16x2* q = (const f16x2*)(hws + (size_t)idx[u] * HWS_LD);
                f16x2 v = q[64 + lane];
                bx = fmaf((float)v.x, m[u], bx);
                by = fmaf((float)v.y, m[u], by);
            }
        }
    }
    float di = dis[i];
    float v0 = ax * di, v1 = ay * di;          // features 2l, 2l+1
    float v2 = bx * di;                        // feature 128+2l (lane<9)
    float v3 = (lane < 8) ? by * di : 0.f;     // feature 129+2l; lane8 slot 145 = pad

    f16x2* o2 = (f16x2*)(agg + (size_t)i * AGG_LD);
    o2[lane] = f16x2{(_Float16)v0, (_Float16)v1};
    if (tl) o2[64 + lane] = f16x2{(_Float16)v2, (_Float16)v3};

    // per-block BN partials (direct-indexed LDS; slots 0..145 written once;
    // 146..151 unwritten -> garbage flows to unread gpart slots only)
    sS[wave][2 * lane] = v0;     sQ[wave][2 * lane] = v0 * v0;
    sS[wave][2 * lane + 1] = v1; sQ[wave][2 * lane + 1] = v1 * v1;
    if (tl) {
        sS[wave][128 + 2 * lane] = v2; sQ[wave][128 + 2 * lane] = v2 * v2;
        sS[wave][129 + 2 * lane] = v3; sQ[wave][129 + 2 * lane] = v3 * v3;
    }
    __syncthreads();
    int bucket = blockIdx.x & (NBKT - 1);
    float* gp = gpart + (size_t)bucket * (2 * AGG_LD);
    for (int idx2 = t; idx2 < 2 * AGG_LD; idx2 += 256) {
        int f = (idx2 < AGG_LD) ? idx2 : idx2 - AGG_LD;
        if (f > HID) continue;  // skip garbage pad slots
        float v = (idx2 < AGG_LD)
                      ? ((sS[0][f] + sS[1][f]) + (sS[2][f] + sS[3][f]))
                      : ((sQ[0][f] + sQ[1][f]) + (sQ[2][f] + sQ[3][f]));
        atomicAdd(&gp[idx2], v);
    }
}

// ---------------- BN coefficients: one wave per feature, reduce 64 buckets,
// then zero the buckets for the next layer's atomics. ----------------

__global__ __launch_bounds__(256) void k_bncoef(float* __restrict__ gpart,
                                                const float* __restrict__ gamma,
                                                const float* __restrict__ beta,
                                                float* __restrict__ AB) {
    int w = blockIdx.x * 4 + (threadIdx.x >> 6);
    int lane = threadIdx.x & 63;
    if (w >= HID) return;
    float* ps = gpart + (size_t)lane * (2 * AGG_LD) + w;
    float s = ps[0];
    float q = ps[AGG_LD];
#pragma unroll
    for (int d = 32; d > 0; d >>= 1) {
        s += __shfl_xor(s, d);
        q += __shfl_xor(q, d);
    }
    ps[0] = 0.f;        // re-zero buckets for next layer
    ps[AGG_LD] = 0.f;
    if (lane == 0) {
        const float inv = 1.f / (float)N_NODES;
        float mu = s * inv;
        float var = q * inv - mu * mu;
        float a = gamma[w] * rsqrtf(var + EPS);
        AB[w] = a;
        AB[HID + w] = beta[w] - mu * a;
    }
}

// ---------------- pool (fused layer-3 BN apply) + MLP, one block per graph ----

__global__ __launch_bounds__(192) void k_pool_mlp(
    const _Float16* __restrict__ agg, const _Float16* __restrict__ h,
    const float* __restrict__ AB, const int* __restrict__ batch,
    const float* __restrict__ W1, const float* __restrict__ b1,
    const float* __restrict__ W2, const float* __restrict__ b2,
    float* __restrict__ out) {
    __shared__ float sH[HID];
    __shared__ float red[128];
    int g = blockIdx.x;
    int lo = 0, hi = N_NODES;
    while (lo < hi) { int m = (lo + hi) >> 1; if (batch[m] < g) lo = m + 1; else hi = m; }
    int s = lo;
    hi = N_NODES;
    while (lo < hi) { int m = (lo + hi) >> 1; if (batch[m] < g + 1) lo = m + 1; else hi = m; }
    int e = lo;
    int f = threadIdx.x;
    if (f < HID) {
        float A = AB[f], B = AB[HID + f];
        float acc = 0.f;
        for (int n = s; n < e; n++) {
            size_t idx = (size_t)n * AGG_LD + f;
            float v = fmaf(A, (float)agg[idx], B);
            acc += fmaxf(v, 0.f) + (float)h[idx];
        }
        sH[f] = acc / fmaxf((float)(e - s), 1.f);
    }
    __syncthreads();
    int t = threadIdx.x;
    float v = 0.f;
    if (t < HID2) {
        float acc = b1[t];
        for (int k = 0; k < HID; k++) acc = fmaf(sH[k], W1[k * HID2 + t], acc);
        v = fmaxf(acc, 0.f) * W2[t];
    }
    if (t < 128) red[t] = v;
    __syncthreads();
    for (int d = 64; d > 0; d >>= 1) {
        if (t < d) red[t] += red[t + d];
        __syncthreads();
    }
    if (t == 0) out[g] = red[0] + b2[0];
}

// ---------------- host launch ----------------

extern "C" void kernel_launch(void* const* d_in, const int* in_sizes, int n_in,
                              void* d_out, int out_size, void* d_ws, size_t ws_size,
                              hipStream_t stream) {
    const int*   x     = (const int*)d_in[0];
    const int*   erow  = (const int*)d_in[1];
    const int*   ecol  = erow + N_EDGES;
    const int*   batch = (const int*)d_in[2];
    const float* emb   = (const float*)d_in[3];
    const float* Wc    = (const float*)d_in[4];
    // d_in[5] = bc: unused — BatchNorm cancels a per-feature constant shift
    const float* gamma = (const float*)d_in[6];
    const float* beta  = (const float*)d_in[7];
    const float* W1    = (const float*)d_in[8];
    const float* b1    = (const float*)d_in[9];
    const float* W2    = (const float*)d_in[10];
    const float* b2    = (const float*)d_in[11];
    float* out = (float*)d_out;

    char* wsb = (char*)d_ws;
    size_t off = 0;
    auto alloc = [&](size_t bytes) -> char* {
        char* p = wsb + off;
        off = (off + bytes + 255) & ~(size_t)255;
        return p;
    };
    int*      hist    = (int*)alloc(N_NODES * 4);
    int*      incl    = (int*)alloc(N_NODES * 4);
    int*      part    = (int*)alloc(64 * 4);
    int*      starts  = (int*)alloc((N_NODES + 1) * 4);
    int*      cursor  = (int*)alloc(N_NODES * 4);
    int*      csr     = (int*)alloc(N_EDGES * 4);
    float*    dis     = (float*)alloc((N_NODES + 64) * 4);  // padded: epilogue float4 reads
    _Float16* h       = (_Float16*)alloc((size_t)N_NODES * AGG_LD * 2);
    _Float16* hws     = (_Float16*)alloc((size_t)N_NODES * HWS_LD * 2);
    _Float16* agg     = (_Float16*)alloc((size_t)N_NODES * AGG_LD * 2);
    float*    gpart   = (float*)alloc((size_t)NBKT * 2 * AGG_LD * 4);
    float*    AB      = (float*)alloc(2 * HID * 4);
    short*    Wfrag   = (short*)alloc((size_t)N_LAYERS * 50 * 1024 * 2);

    const int NB_SCAN = (N_NODES + 1023) / 1024;  // 49
    const int NB_GEMM = (N_NODES + BR - 1) / BR;  // 782

    // CSR build (reused across all layers) + W fragment planes + stat buckets
    hipMemsetAsync(hist, 0, N_NODES * 4, stream);
    hipMemsetAsync(gpart, 0, (size_t)NBKT * 2 * AGG_LD * 4, stream);
    k_hist<<<(N_EDGES + 255) / 256, 256, 0, stream>>>(ecol, hist);
    k_scan1<<<NB_SCAN, 1024, 0, stream>>>(hist, incl, part);
    k_scan2<<<1, 64, 0, stream>>>(part, NB_SCAN);
    k_scan3<<<NB_SCAN, 1024, 0, stream>>>(incl, hist, part, starts, cursor, dis);
    k_fill<<<(N_EDGES + 255) / 256, 256, 0, stream>>>(erow, ecol, cursor, csr);
    k_wfrag<<<N_LAYERS * 50, 64, 0, stream>>>(Wc, Wfrag);

    for (int l = 0; l < N_LAYERS; l++) {
        const short* wfb = Wfrag + (size_t)l * 50 * 1024;
        if (l == 0)
            k_gemm_fused<0><<<NB_GEMM, 512, 0, stream>>>(wfb, dis, x, emb, agg, AB, h, hws);
        else
            k_gemm_fused<1><<<NB_GEMM, 512, 0, stream>>>(wfb, dis, x, emb, agg, AB, h, hws);
        k_agg<<<N_NODES / 4, 256, 0, stream>>>(hws, starts, csr, dis, agg, gpart);
        k_bncoef<<<(HID + 3) / 4, 256, 0, stream>>>(gpart, gamma + l * HID, beta + l * HID, AB);
    }

    k_pool_mlp<<<N_GRAPHS, 192, 0, stream>>>(agg, h, AB, batch, W1, b1, W2, b2, out);
}

// Round 10
// 396.809 us; speedup vs baseline: 3.1597x; 1.0581x over previous
//
#include <hip/hip_runtime.h>

#define N_NODES  50000
#define N_EDGES  500000
#define N_GRAPHS 2000
#define HID      145
#define HID2     72
#define N_LAYERS 4
#define EPS      1e-5f
#define HWS_LD   160   // fp16 gather row stride: 320B = 5 aligned 64B lines
#define AGG_LD   152   // fp16 agg/h row stride: 304B, 16B-aligned rows (f16x8 chunks)
#define BR       64    // rows per GEMM block
#define TSB      168   // fp16 tile stride (halves): 336B rows -> b128 frag reads 2-way (free)
#define NBKT     64    // BN-stat atomic buckets

typedef __attribute__((ext_vector_type(4))) float f32x4;
typedef __attribute__((ext_vector_type(2))) _Float16 f16x2;
typedef __attribute__((ext_vector_type(8))) _Float16 f16x8;

// ---------------- CSR build ----------------

__global__ void k_hist(const int* __restrict__ col, int* __restrict__ hist) {
    int i = blockIdx.x * 256 + threadIdx.x;
    if (i < N_EDGES) atomicAdd(&hist[col[i]], 1);
}

__global__ void k_scan1(const int* __restrict__ cnt, int* __restrict__ incl,
                        int* __restrict__ part) {
    __shared__ int s[1024];
    int i = blockIdx.x * 1024 + threadIdx.x;
    int v = (i < N_NODES) ? cnt[i] : 0;
    s[threadIdx.x] = v;
    __syncthreads();
    for (int d = 1; d < 1024; d <<= 1) {
        int t = (threadIdx.x >= d) ? s[threadIdx.x - d] : 0;
        __syncthreads();
        s[threadIdx.x] += t;
        __syncthreads();
    }
    if (i < N_NODES) incl[i] = s[threadIdx.x];
    if (threadIdx.x == 1023) part[blockIdx.x] = s[1023];
}

__global__ void k_scan2(int* part, int nb) {
    if (threadIdx.x == 0 && blockIdx.x == 0) {
        int acc = 0;
        for (int b = 0; b < nb; b++) { int t = part[b]; part[b] = acc; acc += t; }
    }
}

__global__ void k_scan3(const int* __restrict__ incl, const int* __restrict__ cnt,
                        const int* __restrict__ part, int* __restrict__ starts,
                        int* __restrict__ cursor, float* __restrict__ dis) {
    int i = blockIdx.x * 1024 + threadIdx.x;
    if (i < N_NODES) {
        int st = incl[i] - cnt[i] + part[blockIdx.x];
        starts[i] = st;
        cursor[i] = st;
        dis[i] = rsqrtf((float)(cnt[i] + 1));  // +1 self loop
    }
    if (i == 0) starts[N_NODES] = N_EDGES;
}

__global__ void k_fill(const int* __restrict__ rowv, const int* __restrict__ colv,
                       int* __restrict__ cursor, int* __restrict__ csr) {
    int e = blockIdx.x * 256 + threadIdx.x;
    if (e < N_EDGES) {
        int c = colv[e];
        int p = atomicAdd(&cursor[c], 1);
        csr[p] = rowv[e];
    }
}

// ---------------- W -> fragment-ordered fp16 planes (once per call) ----
// Frag fid = layer*50 + kc*10 + ct: 512 halves;
// lane l, elem j: B[k = kc*32+(l>>4)*8+j][c = ct*16+(l&15)], zero-padded.

__global__ void k_wfrag(const float* __restrict__ Wc, _Float16* __restrict__ Wfrag) {
    int fid = blockIdx.x;                 // 0..199
    int layer = fid / 50, rem = fid - layer * 50;
    int kc = rem / 10, ct = rem - kc * 10;
    int l = threadIdx.x;                  // 0..63
    const float* Wl = Wc + (size_t)layer * HID * HID;
    _Float16* base = Wfrag + (size_t)fid * 512 + l * 8;
#pragma unroll
    for (int j = 0; j < 8; j++) {
        int k = kc * 32 + (l >> 4) * 8 + j;
        int c = ct * 16 + (l & 15);
        float v = (k < HID && c < HID) ? Wl[k * HID + c] : 0.f;
        base[j] = (_Float16)v;
    }
}

// ---------------- fused (BN-apply | embed) + MFMA GEMM ----------------
// Phase 1 (vectorized f16x8): v = relu(A*agg+B)+h_old (MODE 1) or emb[x]
//          (MODE 0); v stored fp16 to h AND the LDS tile (same f16x8 pack —
//          MFMA operand is bit-consistent with stored h, so the only new
//          error vs split-bf16 is fp16(W) quantization, ~1e-4 RMS).
// Phase 2: 8 waves: rt = w&3 (16-row tile), col-half = (w>>2)*5 (5 x 16-col
//          tiles); K = 5 chunks of 32; 1 fp16 MFMA per (ct,kc).
// Epilogue scales by dis, converts to fp16 -> hws (pad cols are exact zeros).

#define MFMA16(a, b, c) __builtin_amdgcn_mfma_f32_16x16x32_f16(a, b, c, 0, 0, 0)

template <int MODE>
__global__ __launch_bounds__(512, 6) void k_gemm_fused(
    const _Float16* __restrict__ wfb, const float* __restrict__ dis,
    const int* __restrict__ x, const float* __restrict__ emb,
    const _Float16* __restrict__ agg, const float* __restrict__ AB,
    _Float16* __restrict__ h, _Float16* __restrict__ hws) {
    __shared__ _Float16 tile[BR * TSB];
    __shared__ float sA[HID], sB[HID];
    int t = threadIdx.x;
    int rbase = blockIdx.x * BR;
    if (MODE == 1 && t < HID) { sA[t] = AB[t]; sB[t] = AB[HID + t]; }
    __syncthreads();
    for (int idx = t; idx < BR * 19; idx += 512) {
        int r = idx / 19;
        int c = idx - r * 19;
        int f0 = c * 8;
        int gr = rbase + r;
        f16x8 hst = {};
        if (gr < N_NODES) {
            size_t base = (size_t)gr * AGG_LD + f0;
            if (MODE == 0) {
                const float* er = emb + x[gr] * HID;
#pragma unroll
                for (int j = 0; j < 8; j++) {
                    int f = f0 + j;
                    hst[j] = (_Float16)((f < HID) ? er[f] : 0.f);
                }
            } else {
                f16x8 av = *(const f16x8*)(agg + base);
                f16x8 hv = *(const f16x8*)(h + base);
#pragma unroll
                for (int j = 0; j < 8; j++) {
                    int f = f0 + j;
                    float vj = 0.f;
                    if (f < HID) {
                        vj = fmaf(sA[f], (float)av[j], sB[f]);
                        vj = fmaxf(vj, 0.f) + (float)hv[j];
                    }
                    hst[j] = (_Float16)vj;
                }
            }
            *(f16x8*)(h + base) = hst;
        }
        *(f16x8*)&tile[r * TSB + f0] = hst;
    }
    // zero K-padding cols [152,160)
    if (t < BR) {
        f16x8 z = {};
        *(f16x8*)&tile[t * TSB + 152] = z;
    }
    __syncthreads();

    int w = t >> 6, l = t & 63;
    int rt = w & 3;
    int c5 = (w >> 2) * 5;                 // col-tile base: 0 or 5
    int arow = rt * 16 + (l & 15);
    int kgrp = (l >> 4) * 8;
    f32x4 acc0 = {}, acc1 = {}, acc2 = {}, acc3 = {}, acc4 = {};
#pragma unroll
    for (int kc = 0; kc < 5; kc++) {
        f16x8 ah = *(const f16x8*)&tile[arow * TSB + kc * 32 + kgrp];
        const _Float16* p = wfb + (size_t)(kc * 10 + c5) * 512 + l * 8;
        f16x8 bh;
#define STEP(ACC, CI)                                                      \
        bh = *(const f16x8*)(p + (CI) * 512);                              \
        ACC = MFMA16(ah, bh, ACC);
        STEP(acc0, 0) STEP(acc1, 1) STEP(acc2, 2) STEP(acc3, 3) STEP(acc4, 4)
#undef STEP
    }
    int rb4 = rbase + rt * 16 + (l >> 4) * 4;
    f32x4 d4 = *(const f32x4*)(dis + rb4);  // dis alloc padded; OOB lanes guarded below
    int colb = c5 * 16 + (l & 15);
#pragma unroll
    for (int r_ = 0; r_ < 4; r_++) {
        int gr = rb4 + r_;
        if (gr < N_NODES) {
            float dd = d4[r_];
            _Float16* row = hws + (size_t)gr * HWS_LD + colb;
            row[0]  = (_Float16)(acc0[r_] * dd);
            row[16] = (_Float16)(acc1[r_] * dd);
            row[32] = (_Float16)(acc2[r_] * dd);
            row[48] = (_Float16)(acc3[r_] * dd);
            row[64] = (_Float16)(acc4[r_] * dd);
        }
    }
}

// ---------------- aggregate + fused BN partial stats ----------------
// agg[i] = dis[i] * (sum_{src in N(i)} hws[src] + hws[i]); one wave per node
// (grid exact: 12500 blocks x 4 waves = 50000). 8-wide predicated edge loop.
// BN stats: per-block LDS reduce (direct-indexed) -> 64-bucket global atomics.

__global__ __launch_bounds__(256) void k_agg(const _Float16* __restrict__ hws,
                                             const int* __restrict__ starts,
                                             const int* __restrict__ csr,
                                             const float* __restrict__ dis,
                                             _Float16* __restrict__ agg,
                                             float* __restrict__ gpart) {
    __shared__ float sS[4][AGG_LD], sQ[4][AGG_LD];
    int t = threadIdx.x;
    int wave = t >> 6;
    int lane = t & 63;
    int i = blockIdx.x * 4 + wave;   // always < N_NODES (exact grid)
    int s = starts[i], e = starts[i + 1];
    bool tl = lane < 9;
    const f16x2* self = (const f16x2*)(hws + (size_t)i * HWS_LD);
    f16x2 sv = self[lane];
    float ax = (float)sv.x, ay = (float)sv.y;
    float bx = 0.f, by = 0.f;
    if (tl) { f16x2 tv = self[64 + lane]; bx = (float)tv.x; by = (float)tv.y; }
    int last = e - 1;
    for (int j = s; j < e; j += 8) {
        int idx[8]; float m[8];
#pragma unroll
        for (int u = 0; u < 8; u++) {
            int jj = j + u;
            bool ok = jj < e;
            idx[u] = csr[ok ? jj : last];
            m[u] = ok ? 1.f : 0.f;
        }
#pragma unroll
        for (int u = 0; u < 8; u++) {
            const f16x2* q = (const f16x2*)(hws + (size_t)idx[u] * HWS_LD);
            f16x2 v = q[lane];
            ax = fmaf((float)v.x, m[u], ax);
            ay = fmaf((float)v.y, m[u], ay);
        }
        if (tl) {
#pragma unroll
            for (int u = 0; u < 8; u++) {
                const f16x2* q = (const f16x2*)(hws + (size_t)idx[u] * HWS_LD);
                f16x2 v = q[64 + lane];
                bx = fmaf((float)v.x, m[u], bx);
                by = fmaf((float)v.y, m[u], by);
            }
        }
    }
    float di = dis[i];
    float v0 = ax * di, v1 = ay * di;          // features 2l, 2l+1
    float v2 = bx * di;                        // feature 128+2l (lane<9)
    float v3 = (lane < 8) ? by * di : 0.f;     // feature 129+2l; lane8 slot 145 = pad

    f16x2* o2 = (f16x2*)(agg + (size_t)i * AGG_LD);
    o2[lane] = f16x2{(_Float16)v0, (_Float16)v1};
    if (tl) o2[64 + lane] = f16x2{(_Float16)v2, (_Float16)v3};

    // per-block BN partials (direct-indexed LDS; slots 0..145 written once;
    // 146..151 unwritten -> garbage flows to skipped gpart slots only)
    sS[wave][2 * lane] = v0;     sQ[wave][2 * lane] = v0 * v0;
    sS[wave][2 * lane + 1] = v1; sQ[wave][2 * lane + 1] = v1 * v1;
    if (tl) {
        sS[wave][128 + 2 * lane] = v2; sQ[wave][128 + 2 * lane] = v2 * v2;
        sS[wave][129 + 2 * lane] = v3; sQ[wave][129 + 2 * lane] = v3 * v3;
    }
    __syncthreads();
    int bucket = blockIdx.x & (NBKT - 1);
    float* gp = gpart + (size_t)bucket * (2 * AGG_LD);
    for (int idx2 = t; idx2 < 2 * AGG_LD; idx2 += 256) {
        int f = (idx2 < AGG_LD) ? idx2 : idx2 - AGG_LD;
        if (f > HID) continue;  // skip garbage pad slots
        float v = (idx2 < AGG_LD)
                      ? ((sS[0][f] + sS[1][f]) + (sS[2][f] + sS[3][f]))
                      : ((sQ[0][f] + sQ[1][f]) + (sQ[2][f] + sQ[3][f]));
        atomicAdd(&gp[idx2], v);
    }
}

// ---------------- BN coefficients: one wave per feature, reduce 64 buckets,
// then zero the buckets for the next layer's atomics. ----------------

__global__ __launch_bounds__(256) void k_bncoef(float* __restrict__ gpart,
                                                const float* __restrict__ gamma,
                                                const float* __restrict__ beta,
                                                float* __restrict__ AB) {
    int w = blockIdx.x * 4 + (threadIdx.x >> 6);
    int lane = threadIdx.x & 63;
    if (w >= HID) return;
    float* ps = gpart + (size_t)lane * (2 * AGG_LD) + w;
    float s = ps[0];
    float q = ps[AGG_LD];
#pragma unroll
    for (int d = 32; d > 0; d >>= 1) {
        s += __shfl_xor(s, d);
        q += __shfl_xor(q, d);
    }
    ps[0] = 0.f;        // re-zero buckets for next layer
    ps[AGG_LD] = 0.f;
    if (lane == 0) {
        const float inv = 1.f / (float)N_NODES;
        float mu = s * inv;
        float var = q * inv - mu * mu;
        float a = gamma[w] * rsqrtf(var + EPS);
        AB[w] = a;
        AB[HID + w] = beta[w] - mu * a;
    }
}

// ---------------- pool (fused layer-3 BN apply) + MLP, one block per graph ----

__global__ __launch_bounds__(192) void k_pool_mlp(
    const _Float16* __restrict__ agg, const _Float16* __restrict__ h,
    const float* __restrict__ AB, const int* __restrict__ batch,
    const float* __restrict__ W1, const float* __restrict__ b1,
    const float* __restrict__ W2, const float* __restrict__ b2,
    float* __restrict__ out) {
    __shared__ float sH[HID];
    __shared__ float red[128];
    int g = blockIdx.x;
    int lo = 0, hi = N_NODES;
    while (lo < hi) { int m = (lo + hi) >> 1; if (batch[m] < g) lo = m + 1; else hi = m; }
    int s = lo;
    hi = N_NODES;
    while (lo < hi) { int m = (lo + hi) >> 1; if (batch[m] < g + 1) lo = m + 1; else hi = m; }
    int e = lo;
    int f = threadIdx.x;
    if (f < HID) {
        float A = AB[f], B = AB[HID + f];
        float acc = 0.f;
        for (int n = s; n < e; n++) {
            size_t idx = (size_t)n * AGG_LD + f;
            float v = fmaf(A, (float)agg[idx], B);
            acc += fmaxf(v, 0.f) + (float)h[idx];
        }
        sH[f] = acc / fmaxf((float)(e - s), 1.f);
    }
    __syncthreads();
    int t = threadIdx.x;
    float v = 0.f;
    if (t < HID2) {
        float acc = b1[t];
        for (int k = 0; k < HID; k++) acc = fmaf(sH[k], W1[k * HID2 + t], acc);
        v = fmaxf(acc, 0.f) * W2[t];
    }
    if (t < 128) red[t] = v;
    __syncthreads();
    for (int d = 64; d > 0; d >>= 1) {
        if (t < d) red[t] += red[t + d];
        __syncthreads();
    }
    if (t == 0) out[g] = red[0] + b2[0];
}

// ---------------- host launch ----------------

extern "C" void kernel_launch(void* const* d_in, const int* in_sizes, int n_in,
                              void* d_out, int out_size, void* d_ws, size_t ws_size,
                              hipStream_t stream) {
    const int*   x     = (const int*)d_in[0];
    const int*   erow  = (const int*)d_in[1];
    const int*   ecol  = erow + N_EDGES;
    const int*   batch = (const int*)d_in[2];
    const float* emb   = (const float*)d_in[3];
    const float* Wc    = (const float*)d_in[4];
    // d_in[5] = bc: unused — BatchNorm cancels a per-feature constant shift
    const float* gamma = (const float*)d_in[6];
    const float* beta  = (const float*)d_in[7];
    const float* W1    = (const float*)d_in[8];
    const float* b1    = (const float*)d_in[9];
    const float* W2    = (const float*)d_in[10];
    const float* b2    = (const float*)d_in[11];
    float* out = (float*)d_out;

    char* wsb = (char*)d_ws;
    size_t off = 0;
    auto alloc = [&](size_t bytes) -> char* {
        char* p = wsb + off;
        off = (off + bytes + 255) & ~(size_t)255;
        return p;
    };
    int*      hist    = (int*)alloc(N_NODES * 4);
    int*      incl    = (int*)alloc(N_NODES * 4);
    int*      part    = (int*)alloc(64 * 4);
    int*      starts  = (int*)alloc((N_NODES + 1) * 4);
    int*      cursor  = (int*)alloc(N_NODES * 4);
    int*      csr     = (int*)alloc(N_EDGES * 4);
    float*    dis     = (float*)alloc((N_NODES + 64) * 4);  // padded: epilogue float4 reads
    _Float16* h       = (_Float16*)alloc((size_t)N_NODES * AGG_LD * 2);
    _Float16* hws     = (_Float16*)alloc((size_t)N_NODES * HWS_LD * 2);
    _Float16* agg     = (_Float16*)alloc((size_t)N_NODES * AGG_LD * 2);
    float*    gpart   = (float*)alloc((size_t)NBKT * 2 * AGG_LD * 4);
    float*    AB      = (float*)alloc(2 * HID * 4);
    _Float16* Wfrag   = (_Float16*)alloc((size_t)N_LAYERS * 50 * 512 * 2);

    const int NB_SCAN = (N_NODES + 1023) / 1024;  // 49
    const int NB_GEMM = (N_NODES + BR - 1) / BR;  // 782

    // CSR build (reused across all layers) + W fragment planes + stat buckets
    hipMemsetAsync(hist, 0, N_NODES * 4, stream);
    hipMemsetAsync(gpart, 0, (size_t)NBKT * 2 * AGG_LD * 4, stream);
    k_hist<<<(N_EDGES + 255) / 256, 256, 0, stream>>>(ecol, hist);
    k_scan1<<<NB_SCAN, 1024, 0, stream>>>(hist, incl, part);
    k_scan2<<<1, 64, 0, stream>>>(part, NB_SCAN);
    k_scan3<<<NB_SCAN, 1024, 0, stream>>>(incl, hist, part, starts, cursor, dis);
    k_fill<<<(N_EDGES + 255) / 256, 256, 0, stream>>>(erow, ecol, cursor, csr);
    k_wfrag<<<N_LAYERS * 50, 64, 0, stream>>>(Wc, Wfrag);

    for (int l = 0; l < N_LAYERS; l++) {
        const _Float16* wfb = Wfrag + (size_t)l * 50 * 512;
        if (l == 0)
            k_gemm_fused<0><<<NB_GEMM, 512, 0, stream>>>(wfb, dis, x, emb, agg, AB, h, hws);
        else
            k_gemm_fused<1><<<NB_GEMM, 512, 0, stream>>>(wfb, dis, x, emb, agg, AB, h, hws);
        k_agg<<<N_NODES / 4, 256, 0, stream>>>(hws, starts, csr, dis, agg, gpart);
        k_bncoef<<<(HID + 3) / 4, 256, 0, stream>>>(gpart, gamma + l * HID, beta + l * HID, AB);
    }

    k_pool_mlp<<<N_GRAPHS, 192, 0, stream>>>(agg, h, AB, batch, W1, b1, W2, b2, out);
}

// Round 11
// 381.629 us; speedup vs baseline: 3.2854x; 1.0398x over previous
//
#include <hip/hip_runtime.h>

#define N_NODES  50000
#define N_EDGES  500000
#define N_GRAPHS 2000
#define HID      145
#define HID2     72
#define N_LAYERS 4
#define EPS      1e-5f
#define HWS_LD   160   // fp16 gather row stride: 320B = 5 aligned 64B lines
#define AGG_LD   152   // fp16 agg/h row stride: 304B, 16B-aligned rows (f16x8 chunks)
#define BR       64    // rows per GEMM block
#define TSB      168   // fp16 tile stride (halves): 336B rows -> b128 frag reads 2-way (free)
#define NBKT     64    // BN-stat atomic buckets (per layer)
#define GPSZ     (NBKT * 2 * AGG_LD)   // floats per layer bucket set
#define NB_FILL  ((N_EDGES + 255) / 256)   // 1954

typedef __attribute__((ext_vector_type(4))) float f32x4;
typedef __attribute__((ext_vector_type(2))) _Float16 f16x2;
typedef __attribute__((ext_vector_type(8))) _Float16 f16x8;

#define RFL(v) __builtin_amdgcn_readfirstlane(v)

// ---------------- zero (hist + all 4 layer bucket sets) ----------------

__global__ void k_zero(int* __restrict__ hist, float* __restrict__ gpart) {
    int i = blockIdx.x * 256 + threadIdx.x;
    if (i < N_NODES) hist[i] = 0;
    if (i < N_LAYERS * GPSZ) gpart[i] = 0.f;
}

// ---------------- CSR build ----------------

__global__ void k_hist(const int* __restrict__ col, int* __restrict__ hist) {
    int i = blockIdx.x * 256 + threadIdx.x;
    if (i < N_EDGES) atomicAdd(&hist[col[i]], 1);
}

__global__ void k_scan1(const int* __restrict__ cnt, int* __restrict__ incl,
                        int* __restrict__ part) {
    __shared__ int s[1024];
    int i = blockIdx.x * 1024 + threadIdx.x;
    int v = (i < N_NODES) ? cnt[i] : 0;
    s[threadIdx.x] = v;
    __syncthreads();
    for (int d = 1; d < 1024; d <<= 1) {
        int t = (threadIdx.x >= d) ? s[threadIdx.x - d] : 0;
        __syncthreads();
        s[threadIdx.x] += t;
        __syncthreads();
    }
    if (i < N_NODES) incl[i] = s[threadIdx.x];
    if (threadIdx.x == 1023) part[blockIdx.x] = s[1023];
}

// scan3 with internal part-prefix (49 parts <= 64 lanes -> wave reduce in wave 0)

__global__ void k_scan3(const int* __restrict__ incl, const int* __restrict__ cnt,
                        const int* __restrict__ part, int* __restrict__ starts,
                        int* __restrict__ cursor, float* __restrict__ dis) {
    __shared__ int sOff;
    int t = threadIdx.x;
    if (t < 64) {
        int v = (t < (int)blockIdx.x && t < 49) ? part[t] : 0;
#pragma unroll
        for (int d = 32; d > 0; d >>= 1) v += __shfl_xor(v, d);
        if (t == 0) sOff = v;
    }
    __syncthreads();
    int off = sOff;
    int i = blockIdx.x * 1024 + t;
    if (i < N_NODES) {
        int st = incl[i] - cnt[i] + off;
        starts[i] = st;
        cursor[i] = st;
        dis[i] = rsqrtf((float)(cnt[i] + 1));  // +1 self loop
    }
    if (i == 0) starts[N_NODES] = N_EDGES;
}

// ---------------- fill CSR + W-fragment pack (merged; blockIdx split) --------
// Frag fid = layer*50 + kc*10 + ct: 512 halves;
// lane l, elem j: B[k = kc*32+(l>>4)*8+j][c = ct*16+(l&15)], zero-padded.

__global__ void k_fill_wfrag(const int* __restrict__ rowv, const int* __restrict__ colv,
                             int* __restrict__ cursor, int* __restrict__ csr,
                             const float* __restrict__ Wc, _Float16* __restrict__ Wfrag) {
    int b = blockIdx.x;
    if (b < NB_FILL) {
        int e = b * 256 + threadIdx.x;
        if (e < N_EDGES) {
            int c = colv[e];
            int p = atomicAdd(&cursor[c], 1);
            csr[p] = rowv[e];
        }
    } else {
        int fid = (b - NB_FILL) * 4 + (threadIdx.x >> 6);   // 0..199
        int l = threadIdx.x & 63;
        int layer = fid / 50, rem = fid - layer * 50;
        int kc = rem / 10, ct = rem - kc * 10;
        const float* Wl = Wc + (size_t)layer * HID * HID;
        _Float16* base = Wfrag + (size_t)fid * 512 + l * 8;
#pragma unroll
        for (int j = 0; j < 8; j++) {
            int k = kc * 32 + (l >> 4) * 8 + j;
            int c = ct * 16 + (l & 15);
            float v = (k < HID && c < HID) ? Wl[k * HID + c] : 0.f;
            base[j] = (_Float16)v;
        }
    }
}

// ---------------- fused (BN-coef + BN-apply | embed) + MFMA GEMM ----------------
// Phase 0 (MODE 1): per-block redundant BN coefficient compute from the
//          previous layer's gpart buckets (75KB, L2-hot broadcast) -> sA/sB.
// Phase 1 (vectorized f16x8): v = relu(A*agg+B)+h_old (MODE 1) or emb[x]
//          (MODE 0); v stored fp16 to h AND the LDS tile (same f16x8 pack).
// Phase 2: 8 waves: rt = w&3 (16-row tile), col-half = (w>>2)*5 (5 x 16-col
//          tiles); K = 5 chunks of 32; 1 fp16 MFMA per (ct,kc).
// Epilogue scales by dis, converts to fp16 -> hws (pad cols are exact zeros).

#define MFMA16(a, b, c) __builtin_amdgcn_mfma_f32_16x16x32_f16(a, b, c, 0, 0, 0)

template <int MODE>
__global__ __launch_bounds__(512, 6) void k_gemm_fused(
    const _Float16* __restrict__ wfb, const float* __restrict__ dis,
    const int* __restrict__ x, const float* __restrict__ emb,
    const _Float16* __restrict__ agg, const float* __restrict__ gpart,
    const float* __restrict__ gamma, const float* __restrict__ beta,
    _Float16* __restrict__ h, _Float16* __restrict__ hws) {
    __shared__ _Float16 tile[BR * TSB];
    __shared__ float sA[HID], sB[HID];
    int t = threadIdx.x;
    int rbase = blockIdx.x * BR;
    if (MODE == 1 && t < HID) {
        float s_ = 0.f, q_ = 0.f;
        for (int b = 0; b < NBKT; b++) {
            s_ += gpart[b * (2 * AGG_LD) + t];
            q_ += gpart[b * (2 * AGG_LD) + AGG_LD + t];
        }
        const float inv = 1.f / (float)N_NODES;
        float mu = s_ * inv;
        float var = q_ * inv - mu * mu;
        float a = gamma[t] * rsqrtf(var + EPS);
        sA[t] = a;
        sB[t] = beta[t] - mu * a;
    }
    __syncthreads();
    for (int idx = t; idx < BR * 19; idx += 512) {
        int r = idx / 19;
        int c = idx - r * 19;
        int f0 = c * 8;
        int gr = rbase + r;
        f16x8 hst = {};
        if (gr < N_NODES) {
            size_t base = (size_t)gr * AGG_LD + f0;
            if (MODE == 0) {
                const float* er = emb + x[gr] * HID;
#pragma unroll
                for (int j = 0; j < 8; j++) {
                    int f = f0 + j;
                    hst[j] = (_Float16)((f < HID) ? er[f] : 0.f);
                }
            } else {
                f16x8 av = *(const f16x8*)(agg + base);
                f16x8 hv = *(const f16x8*)(h + base);
#pragma unroll
                for (int j = 0; j < 8; j++) {
                    int f = f0 + j;
                    float vj = 0.f;
                    if (f < HID) {
                        vj = fmaf(sA[f], (float)av[j], sB[f]);
                        vj = fmaxf(vj, 0.f) + (float)hv[j];
                    }
                    hst[j] = (_Float16)vj;
                }
            }
            *(f16x8*)(h + base) = hst;
        }
        *(f16x8*)&tile[r * TSB + f0] = hst;
    }
    // zero K-padding cols [152,160)
    if (t < BR) {
        f16x8 z = {};
        *(f16x8*)&tile[t * TSB + 152] = z;
    }
    __syncthreads();

    int w = t >> 6, l = t & 63;
    int rt = w & 3;
    int c5 = (w >> 2) * 5;                 // col-tile base: 0 or 5
    int arow = rt * 16 + (l & 15);
    int kgrp = (l >> 4) * 8;
    f32x4 acc0 = {}, acc1 = {}, acc2 = {}, acc3 = {}, acc4 = {};
#pragma unroll
    for (int kc = 0; kc < 5; kc++) {
        f16x8 ah = *(const f16x8*)&tile[arow * TSB + kc * 32 + kgrp];
        const _Float16* p = wfb + (size_t)(kc * 10 + c5) * 512 + l * 8;
        f16x8 bh;
#define STEP(ACC, CI)                                                      \
        bh = *(const f16x8*)(p + (CI) * 512);                              \
        ACC = MFMA16(ah, bh, ACC);
        STEP(acc0, 0) STEP(acc1, 1) STEP(acc2, 2) STEP(acc3, 3) STEP(acc4, 4)
#undef STEP
    }
    int rb4 = rbase + rt * 16 + (l >> 4) * 4;
    f32x4 d4 = *(const f32x4*)(dis + rb4);  // dis alloc padded; OOB lanes guarded below
    int colb = c5 * 16 + (l & 15);
#pragma unroll
    for (int r_ = 0; r_ < 4; r_++) {
        int gr = rb4 + r_;
        if (gr < N_NODES) {
            float dd = d4[r_];
            _Float16* row = hws + (size_t)gr * HWS_LD + colb;
            row[0]  = (_Float16)(acc0[r_] * dd);
            row[16] = (_Float16)(acc1[r_] * dd);
            row[32] = (_Float16)(acc2[r_] * dd);
            row[48] = (_Float16)(acc3[r_] * dd);
            row[64] = (_Float16)(acc4[r_] * dd);
        }
    }
}

// ---------------- aggregate + fused BN partial stats ----------------
// agg[i] = dis[i] * (sum_{src in N(i)} hws[src] + hws[i]); one wave per node
// (grid exact: 12500 blocks x 4 waves = 50000). 8-wide predicated edge loop.
// All wave-uniform values forced to SGPRs via readfirstlane: csr/starts become
// s_loads, gather row bases become saddr-form loads (no per-lane 64b addr math).
// BN stats: per-block LDS reduce (direct-indexed) -> 64-bucket global atomics.

__global__ __launch_bounds__(256) void k_agg(const _Float16* __restrict__ hws,
                                             const int* __restrict__ starts,
                                             const int* __restrict__ csr,
                                             const float* __restrict__ dis,
                                             _Float16* __restrict__ agg,
                                             float* __restrict__ gpart) {
    __shared__ float sS[4][AGG_LD], sQ[4][AGG_LD];
    int t = threadIdx.x;
    int wave = t >> 6;
    int lane = t & 63;
    int i = RFL(blockIdx.x * 4 + wave);   // always < N_NODES (exact grid)
    int s = RFL(starts[i]);
    int e = RFL(starts[i + 1]);
    bool tl = lane < 9;
    const f16x2* self = (const f16x2*)(hws + (size_t)i * HWS_LD);
    f16x2 sv = self[lane];
    float ax = (float)sv.x, ay = (float)sv.y;
    float bx = 0.f, by = 0.f;
    if (tl) { f16x2 tv = self[64 + lane]; bx = (float)tv.x; by = (float)tv.y; }
    int last = e - 1;
    for (int j = s; j < e; j += 8) {
        int rb[8]; float m[8];
#pragma unroll
        for (int u = 0; u < 8; u++) {
            int jj = j + u;
            bool ok = jj < e;
            rb[u] = RFL(csr[ok ? jj : last]) * HWS_LD;   // scalar row base (elems)
            m[u] = ok ? 1.f : 0.f;
        }
#pragma unroll
        for (int u = 0; u < 8; u++) {
            f16x2 v = ((const f16x2*)(hws + rb[u]))[lane];
            ax = fmaf((float)v.x, m[u], ax);
            ay = fmaf((float)v.y, m[u], ay);
        }
        if (tl) {
#pragma unroll
            for (int u = 0; u < 8; u++) {
                f16x2 v = ((const f16x2*)(hws + rb[u]))[64 + lane];
                bx = fmaf((float)v.x, m[u], bx);
                by = fmaf((float)v.y, m[u], by);
            }
        }
    }
    float di = dis[i];
    float v0 = ax * di, v1 = ay * di;          // features 2l, 2l+1
    float v2 = bx * di;                        // feature 128+2l (lane<9)
    float v3 = (lane < 8) ? by * di : 0.f;     // feature 129+2l; lane8 slot 145 = pad

    f16x2* o2 = (f16x2*)(agg + (size_t)i * AGG_LD);
    o2[lane] = f16x2{(_Float16)v0, (_Float16)v1};
    if (tl) o2[64 + lane] = f16x2{(_Float16)v2, (_Float16)v3};

    // per-block BN partials (direct-indexed LDS; slots 0..145 written once;
    // 146..151 unwritten -> garbage flows to skipped gpart slots only)
    sS[wave][2 * lane] = v0;     sQ[wave][2 * lane] = v0 * v0;
    sS[wave][2 * lane + 1] = v1; sQ[wave][2 * lane + 1] = v1 * v1;
    if (tl) {
        sS[wave][128 + 2 * lane] = v2; sQ[wave][128 + 2 * lane] = v2 * v2;
        sS[wave][129 + 2 * lane] = v3; sQ[wave][129 + 2 * lane] = v3 * v3;
    }
    __syncthreads();
    int bucket = blockIdx.x & (NBKT - 1);
    float* gp = gpart + (size_t)bucket * (2 * AGG_LD);
    for (int idx2 = t; idx2 < 2 * AGG_LD; idx2 += 256) {
        int f = (idx2 < AGG_LD) ? idx2 : idx2 - AGG_LD;
        if (f > HID) continue;  // skip garbage pad slots
        float v = (idx2 < AGG_LD)
                      ? ((sS[0][f] + sS[1][f]) + (sS[2][f] + sS[3][f]))
                      : ((sQ[0][f] + sQ[1][f]) + (sQ[2][f] + sQ[3][f]));
        atomicAdd(&gp[idx2], v);
    }
}

// ---------------- BN coefficients (layer 3 only, feeds pool) ----------------

__global__ __launch_bounds__(256) void k_bncoef(const float* __restrict__ gpart,
                                                const float* __restrict__ gamma,
                                                const float* __restrict__ beta,
                                                float* __restrict__ AB) {
    int w = blockIdx.x * 4 + (threadIdx.x >> 6);
    int lane = threadIdx.x & 63;
    if (w >= HID) return;
    const float* ps = gpart + (size_t)lane * (2 * AGG_LD) + w;
    float s = ps[0];
    float q = ps[AGG_LD];
#pragma unroll
    for (int d = 32; d > 0; d >>= 1) {
        s += __shfl_xor(s, d);
        q += __shfl_xor(q, d);
    }
    if (lane == 0) {
        const float inv = 1.f / (float)N_NODES;
        float mu = s * inv;
        float var = q * inv - mu * mu;
        float a = gamma[w] * rsqrtf(var + EPS);
        AB[w] = a;
        AB[HID + w] = beta[w] - mu * a;
    }
}

// ---------------- pool (fused layer-3 BN apply) + MLP, one block per graph ----

__global__ __launch_bounds__(192) void k_pool_mlp(
    const _Float16* __restrict__ agg, const _Float16* __restrict__ h,
    const float* __restrict__ AB, const int* __restrict__ batch,
    const float* __restrict__ W1, const float* __restrict__ b1,
    const float* __restrict__ W2, const float* __restrict__ b2,
    float* __restrict__ out) {
    __shared__ float sH[HID];
    __shared__ float red[128];
    int g = blockIdx.x;
    int lo = 0, hi = N_NODES;
    while (lo < hi) { int m = (lo + hi) >> 1; if (batch[m] < g) lo = m + 1; else hi = m; }
    int s = lo;
    hi = N_NODES;
    while (lo < hi) { int m = (lo + hi) >> 1; if (batch[m] < g + 1) lo = m + 1; else hi = m; }
    int e = lo;
    int f = threadIdx.x;
    if (f < HID) {
        float A = AB[f], B = AB[HID + f];
        float acc = 0.f;
        for (int n = s; n < e; n++) {
            size_t idx = (size_t)n * AGG_LD + f;
            float v = fmaf(A, (float)agg[idx], B);
            acc += fmaxf(v, 0.f) + (float)h[idx];
        }
        sH[f] = acc / fmaxf((float)(e - s), 1.f);
    }
    __syncthreads();
    int t = threadIdx.x;
    float v = 0.f;
    if (t < HID2) {
        float acc = b1[t];
        for (int k = 0; k < HID; k++) acc = fmaf(sH[k], W1[k * HID2 + t], acc);
        v = fmaxf(acc, 0.f) * W2[t];
    }
    if (t < 128) red[t] = v;
    __syncthreads();
    for (int d = 64; d > 0; d >>= 1) {
        if (t < d) red[t] += red[t + d];
        __syncthreads();
    }
    if (t == 0) out[g] = red[0] + b2[0];
}

// ---------------- host launch ----------------

extern "C" void kernel_launch(void* const* d_in, const int* in_sizes, int n_in,
                              void* d_out, int out_size, void* d_ws, size_t ws_size,
                              hipStream_t stream) {
    const int*   x     = (const int*)d_in[0];
    const int*   erow  = (const int*)d_in[1];
    const int*   ecol  = erow + N_EDGES;
    const int*   batch = (const int*)d_in[2];
    const float* emb   = (const float*)d_in[3];
    const float* Wc    = (const float*)d_in[4];
    // d_in[5] = bc: unused — BatchNorm cancels a per-feature constant shift
    const float* gamma = (const float*)d_in[6];
    const float* beta  = (const float*)d_in[7];
    const float* W1    = (const float*)d_in[8];
    const float* b1    = (const float*)d_in[9];
    const float* W2    = (const float*)d_in[10];
    const float* b2    = (const float*)d_in[11];
    float* out = (float*)d_out;

    char* wsb = (char*)d_ws;
    size_t off = 0;
    auto alloc = [&](size_t bytes) -> char* {
        char* p = wsb + off;
        off = (off + bytes + 255) & ~(size_t)255;
        return p;
    };
    int*      hist    = (int*)alloc(N_NODES * 4);
    int*      incl    = (int*)alloc(N_NODES * 4);
    int*      part    = (int*)alloc(64 * 4);
    int*      starts  = (int*)alloc((N_NODES + 1) * 4);
    int*      cursor  = (int*)alloc(N_NODES * 4);
    int*      csr     = (int*)alloc(N_EDGES * 4);
    float*    dis     = (float*)alloc((N_NODES + 64) * 4);  // padded: epilogue float4 reads
    _Float16* h       = (_Float16*)alloc((size_t)N_NODES * AGG_LD * 2);
    _Float16* hws     = (_Float16*)alloc((size_t)N_NODES * HWS_LD * 2);
    _Float16* agg     = (_Float16*)alloc((size_t)N_NODES * AGG_LD * 2);
    float*    gpart   = (float*)alloc((size_t)N_LAYERS * GPSZ * 4);  // per-layer buckets
    float*    AB      = (float*)alloc(2 * HID * 4);
    _Float16* Wfrag   = (_Float16*)alloc((size_t)N_LAYERS * 50 * 512 * 2);

    const int NB_SCAN = (N_NODES + 1023) / 1024;  // 49
    const int NB_GEMM = (N_NODES + BR - 1) / BR;  // 782
    const int NB_ZERO = (N_LAYERS * GPSZ + 255) / 256;  // covers hist too (77824 > 50000... see kernel)

    // CSR build (reused across all layers) + W fragment planes + stat buckets
    k_zero<<<(N_NODES > N_LAYERS * GPSZ ? (N_NODES + 255) / 256 : NB_ZERO), 256, 0, stream>>>(hist, gpart);
    k_hist<<<(N_EDGES + 255) / 256, 256, 0, stream>>>(ecol, hist);
    k_scan1<<<NB_SCAN, 1024, 0, stream>>>(hist, incl, part);
    k_scan3<<<NB_SCAN, 1024, 0, stream>>>(incl, hist, part, starts, cursor, dis);
    k_fill_wfrag<<<NB_FILL + 50, 256, 0, stream>>>(erow, ecol, cursor, csr, Wc, Wfrag);

    for (int l = 0; l < N_LAYERS; l++) {
        const _Float16* wfb = Wfrag + (size_t)l * 50 * 512;
        if (l == 0)
            k_gemm_fused<0><<<NB_GEMM, 512, 0, stream>>>(
                wfb, dis, x, emb, agg, nullptr, nullptr, nullptr, h, hws);
        else
            k_gemm_fused<1><<<NB_GEMM, 512, 0, stream>>>(
                wfb, dis, x, emb, agg, gpart + (size_t)(l - 1) * GPSZ,
                gamma + (l - 1) * HID, beta + (l - 1) * HID, h, hws);
        k_agg<<<N_NODES / 4, 256, 0, stream>>>(hws, starts, csr, dis, agg,
                                               gpart + (size_t)l * GPSZ);
    }

    k_bncoef<<<(HID + 3) / 4, 256, 0, stream>>>(gpart + (size_t)3 * GPSZ,
                                                gamma + 3 * HID, beta + 3 * HID, AB);
    k_pool_mlp<<<N_GRAPHS, 192, 0, stream>>>(agg, h, AB, batch, W1, b1, W2, b2, out);
}